// Round 1
// baseline (1297.919 us; speedup 1.0000x reference)
//
#include <hip/hip_runtime.h>
#include <math.h>

#define B_ 2
#define S_ 2048
#define D_ 1024
#define H_ 16
#define DK_ 64

// ---------------------------------------------------------------------------
// Kernel 1: per-head projection GEMM (fp32, precision-critical for Q/K).
// Out[b,h,s,k] = sum_d X[b,s,d] * W[h,d,k]
// grid = (H, S/64, B), block = 256. 64x64 tile, BK=16, 4x4 per thread.
// ---------------------------------------------------------------------------
__global__ __launch_bounds__(256) void proj_kernel(
    const float* __restrict__ X, const float* __restrict__ W,
    float* __restrict__ Out)
{
    __shared__ float As[16][68];   // [kk][m], padded to avoid store conflicts
    __shared__ float Bs[16][64];   // [kk][n]
    const int h  = blockIdx.x;
    const int s0 = blockIdx.y * 64;
    const int b  = blockIdx.z;
    const float* Xp = X + ((size_t)b * S_ + s0) * D_;
    const float* Wp = W + (size_t)h * D_ * DK_;
    const int tid = threadIdx.x;
    const int mA = tid >> 2, kA = (tid & 3) * 4;    // A-tile load coords
    const int kB = tid >> 4, nB = (tid & 15) * 4;   // B-tile load coords
    const int tm = (tid >> 4) * 4, tn = (tid & 15) * 4;
    float acc[4][4] = {};
    for (int k0 = 0; k0 < D_; k0 += 16) {
        float4 a = *(const float4*)(Xp + (size_t)mA * D_ + k0 + kA);
        As[kA + 0][mA] = a.x;
        As[kA + 1][mA] = a.y;
        As[kA + 2][mA] = a.z;
        As[kA + 3][mA] = a.w;
        *(float4*)&Bs[kB][nB] =
            *(const float4*)(Wp + (size_t)(k0 + kB) * DK_ + nB);
        __syncthreads();
#pragma unroll
        for (int kk = 0; kk < 16; ++kk) {
            float4 av = *(const float4*)&As[kk][tm];
            float4 bv = *(const float4*)&Bs[kk][tn];
            float am[4] = {av.x, av.y, av.z, av.w};
            float bm[4] = {bv.x, bv.y, bv.z, bv.w};
#pragma unroll
            for (int i = 0; i < 4; ++i)
#pragma unroll
                for (int j = 0; j < 4; ++j)
                    acc[i][j] = fmaf(am[i], bm[j], acc[i][j]);
        }
        __syncthreads();
    }
    float* Op = Out + (((size_t)b * H_ + h) * S_ + s0) * DK_;
#pragma unroll
    for (int i = 0; i < 4; ++i) {
        float4 r = {acc[i][0], acc[i][1], acc[i][2], acc[i][3]};
        *(float4*)(Op + (size_t)(tm + i) * DK_ + tn) = r;
    }
}

// ---------------------------------------------------------------------------
// Kernel 2: flash attention, fp32 (scores are precision-critical: sigma~1024,
// softmax is near-one-hot; bf16 scores would misassign argmax winners).
// grid = (S/64, H, B), block = 256 = 64 q-rows x 4 lanes (16 dims each).
// ---------------------------------------------------------------------------
__global__ __launch_bounds__(256) void attn_kernel(
    const float* __restrict__ qh, const float* __restrict__ kh,
    const float* __restrict__ vh, float* __restrict__ ctx)
{
    __shared__ float Ks[64][64];
    __shared__ float Vs[64][64];
    const int s0 = blockIdx.x * 64;
    const int h  = blockIdx.y;
    const int b  = blockIdx.z;
    const int tid = threadIdx.x;
    const int r = tid >> 2;        // q-row within tile
    const int p = tid & 3;         // 16-dim slice owner
    const size_t bh = ((size_t)b * H_ + h) * S_;

    const float* qp = qh + (bh + s0 + r) * DK_ + p * 16;
    float q[16];
#pragma unroll
    for (int i = 0; i < 16; i += 4)
        *(float4*)&q[i] = *(const float4*)(qp + i);

    float o[16] = {};
    float m = -INFINITY, l = 0.f;
    const float* Kbase = kh + bh * DK_;
    const float* Vbase = vh + bh * DK_;

    for (int kv0 = 0; kv0 < S_; kv0 += 64) {
        const float4* Kp = (const float4*)(Kbase + (size_t)kv0 * DK_);
        const float4* Vp = (const float4*)(Vbase + (size_t)kv0 * DK_);
        float4* Kd = (float4*)&Ks[0][0];
        float4* Vd = (float4*)&Vs[0][0];
        __syncthreads();           // protect previous tile's reads
#pragma unroll
        for (int i = 0; i < 4; ++i) {
            Kd[tid + i * 256] = Kp[tid + i * 256];
            Vd[tid + i * 256] = Vp[tid + i * 256];
        }
        __syncthreads();

        for (int j = 0; j < 64; ++j) {
            float s = 0.f;
            const float* krow = &Ks[j][p * 16];
            float4 k0v = *(const float4*)(krow + 0);
            float4 k1v = *(const float4*)(krow + 4);
            float4 k2v = *(const float4*)(krow + 8);
            float4 k3v = *(const float4*)(krow + 12);
            s = fmaf(q[0], k0v.x, s);  s = fmaf(q[1], k0v.y, s);
            s = fmaf(q[2], k0v.z, s);  s = fmaf(q[3], k0v.w, s);
            s = fmaf(q[4], k1v.x, s);  s = fmaf(q[5], k1v.y, s);
            s = fmaf(q[6], k1v.z, s);  s = fmaf(q[7], k1v.w, s);
            s = fmaf(q[8], k2v.x, s);  s = fmaf(q[9], k2v.y, s);
            s = fmaf(q[10], k2v.z, s); s = fmaf(q[11], k2v.w, s);
            s = fmaf(q[12], k3v.x, s); s = fmaf(q[13], k3v.y, s);
            s = fmaf(q[14], k3v.z, s); s = fmaf(q[15], k3v.w, s);
            s += __shfl_xor(s, 1);
            s += __shfl_xor(s, 2);
            s *= 0.125f;               // 1/sqrt(DK)

            const float* vrow = &Vs[j][p * 16];
            float4 v0v = *(const float4*)(vrow + 0);
            float4 v1v = *(const float4*)(vrow + 4);
            float4 v2v = *(const float4*)(vrow + 8);
            float4 v3v = *(const float4*)(vrow + 12);
            float vv[16] = {v0v.x, v0v.y, v0v.z, v0v.w,
                            v1v.x, v1v.y, v1v.z, v1v.w,
                            v2v.x, v2v.y, v2v.z, v2v.w,
                            v3v.x, v3v.y, v3v.z, v3v.w};
            if (s > m) {
                // new running max: rescale accumulator (rare after warmup)
                float corr = exp2f((m - s) * 1.44269504f);
                l = l * corr + 1.f;
#pragma unroll
                for (int i = 0; i < 16; ++i)
                    o[i] = fmaf(o[i], corr, vv[i]);
                m = s;
            } else {
                float pj = exp2f((s - m) * 1.44269504f);
                l += pj;
#pragma unroll
                for (int i = 0; i < 16; ++i)
                    o[i] = fmaf(pj, vv[i], o[i]);
            }
        }
    }
    const float inv = 1.f / l;
    float* cp = ctx + ((size_t)b * S_ + s0 + r) * D_ + h * DK_ + p * 16;
#pragma unroll
    for (int i = 0; i < 16; i += 4) {
        float4 w = {o[i] * inv, o[i + 1] * inv, o[i + 2] * inv, o[i + 3] * inv};
        *(float4*)(cp + i) = w;
    }
}

// ---------------------------------------------------------------------------
// Kernel 3: output projection. Out[m,n] = sum_k ctx[m,k]*Wo[n,k] + bo[n]
// grid = (D/64, B*S/64), block = 256. Both A and B staged transposed.
// ---------------------------------------------------------------------------
__global__ __launch_bounds__(256) void outproj_kernel(
    const float* __restrict__ ctx, const float* __restrict__ Wo,
    const float* __restrict__ bo, float* __restrict__ Out)
{
    __shared__ float As[16][68];
    __shared__ float Bs[16][68];
    const int n0 = blockIdx.x * 64;
    const int m0 = blockIdx.y * 64;
    const int tid = threadIdx.x;
    const int mA = tid >> 2, kA = (tid & 3) * 4;
    const int tm = (tid >> 4) * 4, tn = (tid & 15) * 4;
    float acc[4][4] = {};
    for (int k0 = 0; k0 < D_; k0 += 16) {
        float4 a = *(const float4*)(ctx + (size_t)(m0 + mA) * D_ + k0 + kA);
        As[kA + 0][mA] = a.x;
        As[kA + 1][mA] = a.y;
        As[kA + 2][mA] = a.z;
        As[kA + 3][mA] = a.w;
        float4 w = *(const float4*)(Wo + (size_t)(n0 + mA) * D_ + k0 + kA);
        Bs[kA + 0][mA] = w.x;
        Bs[kA + 1][mA] = w.y;
        Bs[kA + 2][mA] = w.z;
        Bs[kA + 3][mA] = w.w;
        __syncthreads();
#pragma unroll
        for (int kk = 0; kk < 16; ++kk) {
            float4 av = *(const float4*)&As[kk][tm];
            float4 bv = *(const float4*)&Bs[kk][tn];
            float am[4] = {av.x, av.y, av.z, av.w};
            float bm[4] = {bv.x, bv.y, bv.z, bv.w};
#pragma unroll
            for (int i = 0; i < 4; ++i)
#pragma unroll
                for (int j = 0; j < 4; ++j)
                    acc[i][j] = fmaf(am[i], bm[j], acc[i][j]);
        }
        __syncthreads();
    }
#pragma unroll
    for (int i = 0; i < 4; ++i) {
        float4 r;
        r.x = acc[i][0] + bo[n0 + tn + 0];
        r.y = acc[i][1] + bo[n0 + tn + 1];
        r.z = acc[i][2] + bo[n0 + tn + 2];
        r.w = acc[i][3] + bo[n0 + tn + 3];
        *(float4*)(Out + (size_t)(m0 + tm + i) * D_ + n0 + tn) = r;
    }
}

// ---------------------------------------------------------------------------
extern "C" void kernel_launch(void* const* d_in, const int* in_sizes, int n_in,
                              void* d_out, int out_size, void* d_ws,
                              size_t ws_size, hipStream_t stream)
{
    const float* q   = (const float*)d_in[0];
    const float* k   = (const float*)d_in[1];
    const float* v   = (const float*)d_in[2];
    const float* W_q = (const float*)d_in[3];
    const float* W_k = (const float*)d_in[4];
    const float* W_v = (const float*)d_in[5];
    const float* W_o = (const float*)d_in[6];
    const float* b_o = (const float*)d_in[7];
    float* out = (float*)d_out;

    const size_t per = (size_t)B_ * H_ * S_ * DK_;  // 4,194,304 floats
    float* qh  = (float*)d_ws;
    float* kh  = qh + per;
    float* vh  = kh + per;
    float* ctx = vh + per;  // [B,S,D] layout, 64 MiB total workspace

    dim3 pgrid(H_, S_ / 64, B_);
    proj_kernel<<<pgrid, 256, 0, stream>>>(q, W_q, qh);
    proj_kernel<<<pgrid, 256, 0, stream>>>(k, W_k, kh);
    proj_kernel<<<pgrid, 256, 0, stream>>>(v, W_v, vh);

    dim3 agrid(S_ / 64, H_, B_);
    attn_kernel<<<agrid, 256, 0, stream>>>(qh, kh, vh, ctx);

    dim3 ogrid(D_ / 64, (B_ * S_) / 64);
    outproj_kernel<<<ogrid, 256, 0, stream>>>(ctx, W_o, b_o, out);
}

// Round 2
// 1022.086 us; speedup vs baseline: 1.2699x; 1.2699x over previous
//
#include <hip/hip_runtime.h>
#include <math.h>

#define B_ 2
#define S_ 2048
#define D_ 1024
#define H_ 16
#define DK_ 64
#define LOG2E 1.44269504f

// ---------------------------------------------------------------------------
// Kernel 1: per-head projection GEMM (fp32, precision-critical for Q/K).
// Out[b,h,s,k] = sum_d X[b,s,d] * W[h,d,k]
// grid = (H, S/64, B), block = 256. 64x64 tile, BK=16, 4x4 per thread.
// ---------------------------------------------------------------------------
__global__ __launch_bounds__(256) void proj_kernel(
    const float* __restrict__ X, const float* __restrict__ W,
    float* __restrict__ Out)
{
    __shared__ float As[16][68];   // [kk][m], padded
    __shared__ float Bs[16][64];   // [kk][n]
    const int h  = blockIdx.x;
    const int s0 = blockIdx.y * 64;
    const int b  = blockIdx.z;
    const float* Xp = X + ((size_t)b * S_ + s0) * D_;
    const float* Wp = W + (size_t)h * D_ * DK_;
    const int tid = threadIdx.x;
    const int mA = tid >> 2, kA = (tid & 3) * 4;
    const int kB = tid >> 4, nB = (tid & 15) * 4;
    const int tm = (tid >> 4) * 4, tn = (tid & 15) * 4;
    float acc[4][4] = {};
    for (int k0 = 0; k0 < D_; k0 += 16) {
        float4 a = *(const float4*)(Xp + (size_t)mA * D_ + k0 + kA);
        As[kA + 0][mA] = a.x;
        As[kA + 1][mA] = a.y;
        As[kA + 2][mA] = a.z;
        As[kA + 3][mA] = a.w;
        *(float4*)&Bs[kB][nB] =
            *(const float4*)(Wp + (size_t)(k0 + kB) * DK_ + nB);
        __syncthreads();
#pragma unroll
        for (int kk = 0; kk < 16; ++kk) {
            float4 av = *(const float4*)&As[kk][tm];
            float4 bv = *(const float4*)&Bs[kk][tn];
            float am[4] = {av.x, av.y, av.z, av.w};
            float bm[4] = {bv.x, bv.y, bv.z, bv.w};
#pragma unroll
            for (int i = 0; i < 4; ++i)
#pragma unroll
                for (int j = 0; j < 4; ++j)
                    acc[i][j] = fmaf(am[i], bm[j], acc[i][j]);
        }
        __syncthreads();
    }
    float* Op = Out + (((size_t)b * H_ + h) * S_ + s0) * DK_;
#pragma unroll
    for (int i = 0; i < 4; ++i) {
        float4 r = {acc[i][0], acc[i][1], acc[i][2], acc[i][3]};
        *(float4*)(Op + (size_t)(tm + i) * DK_ + tn) = r;
    }
}

// ---------------------------------------------------------------------------
// Kernel 2: flash attention, fp32, register-tiled GEMM structure.
// grid = (S/64, H, B), block = 256. Each block: 64 q-rows vs all kv.
// Thread owns a 4x4 score tile (rows tm..tm+3, cols tn..tn+3) and a
// 4x4 output tile (rows tm..tm+3, dims tn..tn+3).
// Row groups (4 rows) are owned by 16 consecutive lanes -> shfl_xor 1,2,4,8.
// ---------------------------------------------------------------------------
__global__ __launch_bounds__(256) void attn_kernel(
    const float* __restrict__ qh, const float* __restrict__ kh,
    const float* __restrict__ vh, float* __restrict__ ctx)
{
    __shared__ float Qt[64][68];   // [d][qi]  transposed
    __shared__ float Kt[64][68];   // [d][kj]  transposed
    __shared__ float Vs[64][64];   // [kj][dv] natural
    __shared__ float Pt[64][68];   // [kj][qi] transposed
    const int s0 = blockIdx.x * 64;
    const int h  = blockIdx.y;
    const int b  = blockIdx.z;
    const int tid = threadIdx.x;
    const size_t bh = ((size_t)b * H_ + h) * S_;
    const int tm = (tid >> 4) * 4;     // owned q-rows
    const int tn = (tid & 15) * 4;     // owned cols (scores) / dims (output)
    const int rj  = tid >> 2;          // staging: row 0..63
    const int rd0 = (tid & 3) * 4;     // staging: dim base

    // stage Q transposed (once per block)
    const float* Qg = qh + (bh + s0) * DK_;
#pragma unroll
    for (int t = 0; t < 4; ++t) {
        int d0 = rd0 + t * 16;
        float4 a = *(const float4*)(Qg + (size_t)rj * DK_ + d0);
        Qt[d0 + 0][rj] = a.x;
        Qt[d0 + 1][rj] = a.y;
        Qt[d0 + 2][rj] = a.z;
        Qt[d0 + 3][rj] = a.w;
    }
    float o[4][4] = {};
    float m[4], l[4];
#pragma unroll
    for (int i = 0; i < 4; ++i) { m[i] = -3.0e38f; l[i] = 0.f; }

    const float* Kg = kh + bh * DK_;
    const float* Vg = vh + bh * DK_;
    __syncthreads();

    for (int kv0 = 0; kv0 < S_; kv0 += 64) {
        // ---- stage K (transposed) and V ----
#pragma unroll
        for (int t = 0; t < 4; ++t) {
            int d0 = rd0 + t * 16;
            float4 a = *(const float4*)(Kg + (size_t)(kv0 + rj) * DK_ + d0);
            Kt[d0 + 0][rj] = a.x;
            Kt[d0 + 1][rj] = a.y;
            Kt[d0 + 2][rj] = a.z;
            Kt[d0 + 3][rj] = a.w;
        }
        {
            const float4* Vp = (const float4*)(Vg + (size_t)kv0 * DK_);
            float4* Vd = (float4*)&Vs[0][0];
#pragma unroll
            for (int t = 0; t < 4; ++t)
                Vd[tid + t * 256] = Vp[tid + t * 256];
        }
        __syncthreads();

        // ---- S = Q K^T (64x64x64 tile GEMM) ----
        float acc[4][4] = {};
#pragma unroll 8
        for (int d = 0; d < 64; ++d) {
            float4 av = *(const float4*)&Qt[d][tm];
            float4 bv = *(const float4*)&Kt[d][tn];
            float am[4] = {av.x, av.y, av.z, av.w};
            float bm[4] = {bv.x, bv.y, bv.z, bv.w};
#pragma unroll
            for (int i = 0; i < 4; ++i)
#pragma unroll
                for (int j = 0; j < 4; ++j)
                    acc[i][j] = fmaf(am[i], bm[j], acc[i][j]);
        }

        // ---- online softmax (scaled domain) ----
#pragma unroll
        for (int i = 0; i < 4; ++i) {
#pragma unroll
            for (int j = 0; j < 4; ++j) acc[i][j] *= 0.125f;
            float rmax = fmaxf(fmaxf(acc[i][0], acc[i][1]),
                               fmaxf(acc[i][2], acc[i][3]));
            rmax = fmaxf(rmax, __shfl_xor(rmax, 1));
            rmax = fmaxf(rmax, __shfl_xor(rmax, 2));
            rmax = fmaxf(rmax, __shfl_xor(rmax, 4));
            rmax = fmaxf(rmax, __shfl_xor(rmax, 8));
            float newm = fmaxf(m[i], rmax);
            float corr = __builtin_amdgcn_exp2f((m[i] - newm) * LOG2E);
            float p0 = __builtin_amdgcn_exp2f((acc[i][0] - newm) * LOG2E);
            float p1 = __builtin_amdgcn_exp2f((acc[i][1] - newm) * LOG2E);
            float p2 = __builtin_amdgcn_exp2f((acc[i][2] - newm) * LOG2E);
            float p3 = __builtin_amdgcn_exp2f((acc[i][3] - newm) * LOG2E);
            l[i] = l[i] * corr + (p0 + p1 + p2 + p3);
#pragma unroll
            for (int j = 0; j < 4; ++j) o[i][j] *= corr;
            m[i] = newm;
            Pt[tn + 0][tm + i] = p0;
            Pt[tn + 1][tm + i] = p1;
            Pt[tn + 2][tm + i] = p2;
            Pt[tn + 3][tm + i] = p3;
        }
        __syncthreads();   // Pt visible before PV reads

        // ---- O += P V (64x64x64 tile GEMM) ----
#pragma unroll 8
        for (int j = 0; j < 64; ++j) {
            float4 av = *(const float4*)&Pt[j][tm];
            float4 bv = *(const float4*)&Vs[j][tn];
            float am[4] = {av.x, av.y, av.z, av.w};
            float bm[4] = {bv.x, bv.y, bv.z, bv.w};
#pragma unroll
            for (int i = 0; i < 4; ++i)
#pragma unroll
                for (int jj = 0; jj < 4; ++jj)
                    o[i][jj] = fmaf(am[i], bm[jj], o[i][jj]);
        }
        __syncthreads();   // done reading Kt/Vs/Pt before next staging
    }

    // ---- epilogue: reduce l across the 16 lanes of the row group ----
#pragma unroll
    for (int i = 0; i < 4; ++i) {
        float li = l[i];
        li += __shfl_xor(li, 1);
        li += __shfl_xor(li, 2);
        li += __shfl_xor(li, 4);
        li += __shfl_xor(li, 8);
        float inv = 1.f / li;
        float* cp = ctx + ((size_t)b * S_ + s0 + tm + i) * D_ + h * DK_ + tn;
        float4 w = {o[i][0] * inv, o[i][1] * inv, o[i][2] * inv, o[i][3] * inv};
        *(float4*)cp = w;
    }
}

// ---------------------------------------------------------------------------
// Kernel 3: output projection. Out[m,n] = sum_k ctx[m,k]*Wo[n,k] + bo[n]
// ---------------------------------------------------------------------------
__global__ __launch_bounds__(256) void outproj_kernel(
    const float* __restrict__ ctx, const float* __restrict__ Wo,
    const float* __restrict__ bo, float* __restrict__ Out)
{
    __shared__ float As[16][68];
    __shared__ float Bs[16][68];
    const int n0 = blockIdx.x * 64;
    const int m0 = blockIdx.y * 64;
    const int tid = threadIdx.x;
    const int mA = tid >> 2, kA = (tid & 3) * 4;
    const int tm = (tid >> 4) * 4, tn = (tid & 15) * 4;
    float acc[4][4] = {};
    for (int k0 = 0; k0 < D_; k0 += 16) {
        float4 a = *(const float4*)(ctx + (size_t)(m0 + mA) * D_ + k0 + kA);
        As[kA + 0][mA] = a.x;
        As[kA + 1][mA] = a.y;
        As[kA + 2][mA] = a.z;
        As[kA + 3][mA] = a.w;
        float4 w = *(const float4*)(Wo + (size_t)(n0 + mA) * D_ + k0 + kA);
        Bs[kA + 0][mA] = w.x;
        Bs[kA + 1][mA] = w.y;
        Bs[kA + 2][mA] = w.z;
        Bs[kA + 3][mA] = w.w;
        __syncthreads();
#pragma unroll
        for (int kk = 0; kk < 16; ++kk) {
            float4 av = *(const float4*)&As[kk][tm];
            float4 bv = *(const float4*)&Bs[kk][tn];
            float am[4] = {av.x, av.y, av.z, av.w};
            float bm[4] = {bv.x, bv.y, bv.z, bv.w};
#pragma unroll
            for (int i = 0; i < 4; ++i)
#pragma unroll
                for (int j = 0; j < 4; ++j)
                    acc[i][j] = fmaf(am[i], bm[j], acc[i][j]);
        }
        __syncthreads();
    }
#pragma unroll
    for (int i = 0; i < 4; ++i) {
        float4 r;
        r.x = acc[i][0] + bo[n0 + tn + 0];
        r.y = acc[i][1] + bo[n0 + tn + 1];
        r.z = acc[i][2] + bo[n0 + tn + 2];
        r.w = acc[i][3] + bo[n0 + tn + 3];
        *(float4*)(Out + (size_t)(m0 + tm + i) * D_ + n0 + tn) = r;
    }
}

// ---------------------------------------------------------------------------
extern "C" void kernel_launch(void* const* d_in, const int* in_sizes, int n_in,
                              void* d_out, int out_size, void* d_ws,
                              size_t ws_size, hipStream_t stream)
{
    const float* q   = (const float*)d_in[0];
    const float* k   = (const float*)d_in[1];
    const float* v   = (const float*)d_in[2];
    const float* W_q = (const float*)d_in[3];
    const float* W_k = (const float*)d_in[4];
    const float* W_v = (const float*)d_in[5];
    const float* W_o = (const float*)d_in[6];
    const float* b_o = (const float*)d_in[7];
    float* out = (float*)d_out;

    const size_t per = (size_t)B_ * H_ * S_ * DK_;
    float* qh  = (float*)d_ws;
    float* kh  = qh + per;
    float* vh  = kh + per;
    float* ctx = vh + per;

    dim3 pgrid(H_, S_ / 64, B_);
    proj_kernel<<<pgrid, 256, 0, stream>>>(q, W_q, qh);
    proj_kernel<<<pgrid, 256, 0, stream>>>(k, W_k, kh);
    proj_kernel<<<pgrid, 256, 0, stream>>>(v, W_v, vh);

    dim3 agrid(S_ / 64, H_, B_);
    attn_kernel<<<agrid, 256, 0, stream>>>(qh, kh, vh, ctx);

    dim3 ogrid(D_ / 64, (B_ * S_) / 64);
    outproj_kernel<<<ogrid, 256, 0, stream>>>(ctx, W_o, b_o, out);
}

// Round 3
// 297.421 us; speedup vs baseline: 4.3639x; 3.4365x over previous
//
#include <hip/hip_runtime.h>
#include <math.h>

#define B_ 2
#define S_ 2048
#define D_ 1024
#define H_ 16
#define ATTN_C 0.18033688011f   // log2(e)/8  (fold 1/sqrt(64) into exp2)

typedef unsigned short ushort_t;
typedef __attribute__((ext_vector_type(8))) short short8;
typedef __attribute__((ext_vector_type(4))) short short4v;
typedef __attribute__((ext_vector_type(4))) float f32x4;
typedef __attribute__((ext_vector_type(16))) float f32x16;
typedef __attribute__((ext_vector_type(2))) unsigned int uint2v;
typedef __attribute__((ext_vector_type(4))) unsigned int uint4v;

#define MFMA(A, B, C) __builtin_amdgcn_mfma_f32_32x32x16_bf16((A), (B), (C), 0, 0, 0)
#define Z16 {0.f,0.f,0.f,0.f,0.f,0.f,0.f,0.f,0.f,0.f,0.f,0.f,0.f,0.f,0.f,0.f}

__device__ __forceinline__ ushort_t bf16rn(float x) {
    unsigned int u = __builtin_bit_cast(unsigned int, x);
    u += 0x7FFFu + ((u >> 16) & 1u);
    return (ushort_t)(u >> 16);
}
__device__ __forceinline__ float bf16tof(ushort_t h) {
    return __builtin_bit_cast(float, (unsigned int)h << 16);
}
__device__ __forceinline__ unsigned cvtpk(float lo, float hi) {
    unsigned r;
    asm("v_cvt_pk_bf16_f32 %0, %1, %2" : "=v"(r) : "v"(lo), "v"(hi));
    return r;
}

// ---------------------------------------------------------------------------
// cvtw: W_q/W_k -> transposed hi/lo bf16 [h][n][1024]; W_v -> transposed hi.
// grid (16 dtiles, 16 h, 3 mat), block 256.
// ---------------------------------------------------------------------------
__global__ __launch_bounds__(256) void cvtw_kernel(
    const float* __restrict__ Wq, const float* __restrict__ Wk,
    const float* __restrict__ Wv,
    ushort_t* __restrict__ wqh, ushort_t* __restrict__ wql,
    ushort_t* __restrict__ wkh, ushort_t* __restrict__ wkl,
    ushort_t* __restrict__ wvh)
{
    __shared__ float T[64][68];
    const int dt = blockIdx.x, h = blockIdx.y, mat = blockIdx.z;
    const int tid = threadIdx.x;
    const float* W = mat == 0 ? Wq : mat == 1 ? Wk : Wv;
    const float* Wb = W + ((size_t)h * 1024 + dt * 64) * 64;
#pragma unroll
    for (int u = 0; u < 4; ++u) {
        int idx = tid + u * 256;
        int d = idx >> 4, c4 = idx & 15;
        f32x4 v = *(const f32x4*)(Wb + (size_t)d * 64 + c4 * 4);
        T[d][c4 * 4 + 0] = v.x; T[d][c4 * 4 + 1] = v.y;
        T[d][c4 * 4 + 2] = v.z; T[d][c4 * 4 + 3] = v.w;
    }
    __syncthreads();
    ushort_t* oh = mat == 0 ? wqh : mat == 1 ? wkh : wvh;
    ushort_t* ol = mat == 0 ? wql : mat == 1 ? wkl : nullptr;
#pragma unroll
    for (int u = 0; u < 4; ++u) {
        int idx = tid + u * 256;
        int n = idx >> 4, c4 = idx & 15;
        float v0 = T[c4 * 4 + 0][n], v1 = T[c4 * 4 + 1][n];
        float v2 = T[c4 * 4 + 2][n], v3 = T[c4 * 4 + 3][n];
        ushort_t h0 = bf16rn(v0), h1 = bf16rn(v1), h2 = bf16rn(v2), h3 = bf16rn(v3);
        size_t off = ((size_t)h * 64 + n) * 1024 + dt * 64 + c4 * 4;
        short4v hv = {(short)h0, (short)h1, (short)h2, (short)h3};
        *(short4v*)(oh + off) = hv;
        if (ol) {
            short4v lv = {(short)bf16rn(v0 - bf16tof(h0)), (short)bf16rn(v1 - bf16tof(h1)),
                          (short)bf16rn(v2 - bf16tof(h2)), (short)bf16rn(v3 - bf16tof(h3))};
            *(short4v*)(ol + off) = lv;
        }
    }
}

// W_o fp32 -> bf16 copy (natural [n][k] layout already matches B-frag needs)
__global__ __launch_bounds__(256) void cvtwo_kernel(
    const float* __restrict__ Wo, ushort_t* __restrict__ wob)
{
    size_t idx = (size_t)blockIdx.x * 256 + threadIdx.x;
    f32x4 v = *(const f32x4*)(Wo + idx * 4);
    short4v o = {(short)bf16rn(v.x), (short)bf16rn(v.y),
                 (short)bf16rn(v.z), (short)bf16rn(v.w)};
    *(short4v*)(wob + idx * 4) = o;
}

// ---------------------------------------------------------------------------
// proj: Out[b,h,s,n] = sum_d X[b,s,d] * W[h,d,n].  Q/K: split-3 MFMA -> hi/lo
// out.  V: single bf16.  grid (16 s-tiles, 16 h, pr*2+b), block 128 (2 waves,
// each wave 64s x 64n).  BK=64, 32x32x16 MFMA.
// ---------------------------------------------------------------------------
__global__ __launch_bounds__(128, 2) void proj_kernel(
    const float* __restrict__ Xq, const float* __restrict__ Xk,
    const float* __restrict__ Xv,
    const ushort_t* __restrict__ Wh_q, const ushort_t* __restrict__ Wl_q,
    const ushort_t* __restrict__ Wh_k, const ushort_t* __restrict__ Wl_k,
    const ushort_t* __restrict__ Wh_v,
    ushort_t* __restrict__ Oq_h, ushort_t* __restrict__ Oq_l,
    ushort_t* __restrict__ Ok_h, ushort_t* __restrict__ Ok_l,
    ushort_t* __restrict__ Ov)
{
    __shared__ __align__(16) ushort_t Xs[128 * 128];  // [s][isLo*64+d] ^ ((s&15)<<3)
    __shared__ __align__(16) ushort_t Ws[64 * 128];   // [n][isLo*64+d] ^ ((n&15)<<3)
    const int tid = threadIdx.x;
    const int wv = tid >> 6, lane = tid & 63;
    const int lo32 = lane & 31, g = lane >> 5;
    const int s0 = blockIdx.x * 128;
    const int h = blockIdx.y;
    const int pr = blockIdx.z >> 1, b = blockIdx.z & 1;
    const bool split = (pr != 2);
    const float* X = pr == 0 ? Xq : pr == 1 ? Xk : Xv;
    const ushort_t* Wh = pr == 0 ? Wh_q : pr == 1 ? Wh_k : Wh_v;
    const ushort_t* Wl = pr == 0 ? Wl_q : pr == 1 ? Wl_k : Wh_v;
    const float* Xb = X + ((size_t)b * S_ + s0) * D_;
    const ushort_t* Whb = Wh + (size_t)h * 64 * 1024;
    const ushort_t* Wlb = Wl + (size_t)h * 64 * 1024;
    f32x16 a00 = Z16, a01 = Z16, a10 = Z16, a11 = Z16;

    for (int d0 = 0; d0 < D_; d0 += 64) {
        __syncthreads();
        // stage X (fp32 -> hi/lo bf16)
#pragma unroll
        for (int u = 0; u < 16; ++u) {
            int idx = tid + u * 128;
            int s = idx >> 4, c4 = idx & 15;
            f32x4 xv = *(const f32x4*)(Xb + (size_t)s * D_ + d0 + c4 * 4);
            ushort_t h0 = bf16rn(xv.x), h1 = bf16rn(xv.y), h2 = bf16rn(xv.z), h3 = bf16rn(xv.w);
            ushort_t l0 = bf16rn(xv.x - bf16tof(h0)), l1 = bf16rn(xv.y - bf16tof(h1));
            ushort_t l2 = bf16rn(xv.z - bf16tof(h2)), l3 = bf16rn(xv.w - bf16tof(h3));
            int base = s * 128 + c4 * 4;
            int sw = (s & 15) << 3;
            uint2v hw = {((unsigned)h1 << 16) | h0, ((unsigned)h3 << 16) | h2};
            uint2v lw = {((unsigned)l1 << 16) | l0, ((unsigned)l3 << 16) | l2};
            *(uint2v*)&Xs[base ^ sw] = hw;
            *(uint2v*)&Xs[(base + 64) ^ sw] = lw;
        }
        // stage W (pre-converted, pre-transposed)
#pragma unroll
        for (int u = 0; u < 8; ++u) {
            int idx = tid + u * 128;
            int isLo = idx >> 9, rem = idx & 511;
            int n = rem >> 3, c8 = rem & 7;
            const ushort_t* src = isLo ? Wlb : Whb;
            short8 w8 = *(const short8*)(src + (size_t)n * 1024 + d0 + c8 * 8);
            *(short8*)&Ws[(n * 128 + isLo * 64 + c8 * 8) ^ ((n & 15) << 3)] = w8;
        }
        __syncthreads();
#pragma unroll
        for (int ks = 0; ks < 4; ++ks) {
            int coff = ks * 16 + g * 8;
            int r0 = wv * 64 + lo32, r1 = r0 + 32;
            short8 a0h = *(const short8*)&Xs[(r0 * 128 + coff) ^ ((r0 & 15) << 3)];
            short8 a0l = *(const short8*)&Xs[(r0 * 128 + 64 + coff) ^ ((r0 & 15) << 3)];
            short8 a1h = *(const short8*)&Xs[(r1 * 128 + coff) ^ ((r1 & 15) << 3)];
            short8 a1l = *(const short8*)&Xs[(r1 * 128 + 64 + coff) ^ ((r1 & 15) << 3)];
            int n1 = lo32 + 32;
            short8 b0h = *(const short8*)&Ws[(lo32 * 128 + coff) ^ ((lo32 & 15) << 3)];
            short8 b0l = *(const short8*)&Ws[(lo32 * 128 + 64 + coff) ^ ((lo32 & 15) << 3)];
            short8 b1h = *(const short8*)&Ws[(n1 * 128 + coff) ^ ((n1 & 15) << 3)];
            short8 b1l = *(const short8*)&Ws[(n1 * 128 + 64 + coff) ^ ((n1 & 15) << 3)];
            a00 = MFMA(a0h, b0h, a00);
            a01 = MFMA(a0h, b1h, a01);
            a10 = MFMA(a1h, b0h, a10);
            a11 = MFMA(a1h, b1h, a11);
            if (split) {
                a00 = MFMA(a0h, b0l, a00); a00 = MFMA(a0l, b0h, a00);
                a01 = MFMA(a0h, b1l, a01); a01 = MFMA(a0l, b1h, a01);
                a10 = MFMA(a1h, b0l, a10); a10 = MFMA(a1l, b0h, a10);
                a11 = MFMA(a1h, b1l, a11); a11 = MFMA(a1l, b1h, a11);
            }
        }
    }
    ushort_t* OH = pr == 0 ? Oq_h : pr == 1 ? Ok_h : Ov;
    ushort_t* OL = pr == 0 ? Oq_l : pr == 1 ? Ok_l : Ov;
    const size_t obase = ((size_t)b * H_ + h) * S_ + s0;
#define PROJ_STORE(ACC, MT, NT)                                             \
    _Pragma("unroll")                                                       \
    for (int r = 0; r < 16; ++r) {                                          \
        int s_loc = wv * 64 + (MT) * 32 + (r & 3) + 8 * (r >> 2) + 4 * g;   \
        int n = (NT) * 32 + lo32;                                           \
        float val = ACC[r];                                                 \
        size_t off = (obase + s_loc) * 64 + n;                              \
        if (split) {                                                        \
            ushort_t hh = bf16rn(val);                                      \
            OH[off] = hh;                                                   \
            OL[off] = bf16rn(val - bf16tof(hh));                            \
        } else OH[off] = bf16rn(val);                                       \
    }
    PROJ_STORE(a00, 0, 0)
    PROJ_STORE(a01, 0, 1)
    PROJ_STORE(a10, 1, 0)
    PROJ_STORE(a11, 1, 1)
#undef PROJ_STORE
}

// ---------------------------------------------------------------------------
// attn: swapped QK^T (S^T = mfma(K,Q), col=q per lane), per-lane online
// softmax, P exchanged cross-half via cvt_pk + shfl_xor(32), O^T = mfma(Vt,P).
// grid (16 q-tiles of 128, 16 h, 2 b), block 256 (4 waves x 32 q).
// ---------------------------------------------------------------------------
__global__ __launch_bounds__(256, 2) void attn_kernel(
    const ushort_t* __restrict__ qh_h, const ushort_t* __restrict__ qh_l,
    const ushort_t* __restrict__ kh_h, const ushort_t* __restrict__ kh_l,
    const ushort_t* __restrict__ vh, ushort_t* __restrict__ ctxb)
{
    __shared__ __align__(16) ushort_t Ks[64 * 128];  // [kv][isLo*64+d] ^ ((kv&15)<<3)
    __shared__ __align__(16) ushort_t Vt[64 * 64];   // [d][kv] ^ ((d&7)<<3)
    __shared__ __align__(16) float Oep[4 * 32 * 64]; // per-wave O^T transpose
    const int tid = threadIdx.x;
    const int wv = tid >> 6, lane = tid & 63;
    const int lo32 = lane & 31, g = lane >> 5;
    const int s0 = blockIdx.x * 128;
    const int h = blockIdx.y, b = blockIdx.z;
    const size_t bhs = ((size_t)b * H_ + h) * S_ * 64;

    // Q fragments straight from global (held in regs the whole kernel)
    const ushort_t* Qrh = qh_h + bhs + (size_t)(s0 + wv * 32 + lo32) * 64;
    const ushort_t* Qrl = qh_l + bhs + (size_t)(s0 + wv * 32 + lo32) * 64;
    short8 qfh[4], qfl[4];
#pragma unroll
    for (int ks = 0; ks < 4; ++ks) {
        qfh[ks] = *(const short8*)(Qrh + ks * 16 + g * 8);
        qfl[ks] = *(const short8*)(Qrl + ks * 16 + g * 8);
    }
    const ushort_t* Kgh = kh_h + bhs;
    const ushort_t* Kgl = kh_l + bhs;
    const ushort_t* Vg = vh + bhs;

    f32x16 o0 = Z16, o1 = Z16;
    float mrun = -3.0e38f, lrun = 0.0f;

    for (int kv0 = 0; kv0 < S_; kv0 += 64) {
        __syncthreads();
        // stage K hi/lo
#pragma unroll
        for (int rep = 0; rep < 2; ++rep) {
            int idx = tid + rep * 256;
            int row = idx >> 3, c8 = idx & 7;
            short8 ah = *(const short8*)(Kgh + (size_t)(kv0 + row) * 64 + c8 * 8);
            short8 al = *(const short8*)(Kgl + (size_t)(kv0 + row) * 64 + c8 * 8);
            int sw = (row & 15) << 3;
            *(short8*)&Ks[(row * 128 + c8 * 8) ^ sw] = ah;
            *(short8*)&Ks[(row * 128 + 64 + c8 * 8) ^ sw] = al;
        }
        // stage V transposed
        {
            int kvp = tid & 31, d8 = tid >> 5;
            const ushort_t* vp = Vg + (size_t)(kv0 + 2 * kvp) * 64 + d8 * 8;
            short8 va = *(const short8*)(vp);
            short8 vb = *(const short8*)(vp + 64);
#pragma unroll
            for (int i = 0; i < 8; ++i) {
                int d = d8 * 8 + i;
                unsigned wrd = ((unsigned)(ushort_t)vb[i] << 16) | (ushort_t)va[i];
                *(unsigned*)&Vt[(d * 64 + 2 * kvp) ^ ((d & 7) << 3)] = wrd;
            }
        }
        __syncthreads();
#pragma unroll
        for (int ch = 0; ch < 2; ++ch) {
            int kvb = ch * 32;
            f32x16 st = Z16;
#pragma unroll
            for (int ks = 0; ks < 4; ++ks) {
                int krow = kvb + lo32;
                int base = krow * 128 + ks * 16 + g * 8;
                int sw = (krow & 15) << 3;
                short8 kfh = *(const short8*)&Ks[base ^ sw];
                short8 kfl = *(const short8*)&Ks[(base + 64) ^ sw];
                st = MFMA(kfh, qfh[ks], st);
                st = MFMA(kfh, qfl[ks], st);
                st = MFMA(kfl, qfh[ks], st);
            }
            // per-lane online softmax (lane owns one q column)
            float cmax = st[0];
#pragma unroll
            for (int r = 1; r < 16; ++r) cmax = fmaxf(cmax, st[r]);
            cmax = fmaxf(cmax, __shfl_xor(cmax, 32));
            float mnew = fmaxf(mrun, cmax);
            float corr = exp2f((mrun - mnew) * ATTN_C);
            float p[16];
            float ls = 0.f;
#pragma unroll
            for (int r = 0; r < 16; ++r) {
                p[r] = exp2f((st[r] - mnew) * ATTN_C);
                ls += p[r];
            }
            lrun = lrun * corr + ls;
#pragma unroll
            for (int r = 0; r < 16; ++r) { o0[r] *= corr; o1[r] *= corr; }
            mrun = mnew;
            // P^T -> B-frag via pack + cross-half exchange, then PV
#pragma unroll
            for (int ks2 = 0; ks2 < 2; ++ks2) {
                int rr = ks2 * 8;
                unsigned w0 = cvtpk(p[rr + 0], p[rr + 1]);
                unsigned w1 = cvtpk(p[rr + 2], p[rr + 3]);
                unsigned w2 = cvtpk(p[rr + 4], p[rr + 5]);
                unsigned w3 = cvtpk(p[rr + 6], p[rr + 7]);
                unsigned x0 = (unsigned)__shfl_xor((int)w0, 32);
                unsigned x1 = (unsigned)__shfl_xor((int)w1, 32);
                unsigned x2 = (unsigned)__shfl_xor((int)w2, 32);
                unsigned x3 = (unsigned)__shfl_xor((int)w3, 32);
                uint4v pw = {g ? x2 : w0, g ? x3 : w1, g ? w2 : x0, g ? w3 : x1};
                short8 pfrag = __builtin_bit_cast(short8, pw);
                int kvf = kvb + ks2 * 16 + g * 8;
                int vsw = (lo32 & 7) << 3;
                short8 vf0 = *(const short8*)&Vt[(lo32 * 64 + kvf) ^ vsw];
                short8 vf1 = *(const short8*)&Vt[((lo32 + 32) * 64 + kvf) ^ vsw];
                o0 = MFMA(vf0, pfrag, o0);
                o1 = MFMA(vf1, pfrag, o1);
            }
        }
    }
    // epilogue: normalize, transpose O^T -> ctx rows via per-wave LDS slice
    lrun += __shfl_xor(lrun, 32);
    float inv = 1.0f / lrun;
    float* Oe = Oep + wv * 2048;
#pragma unroll
    for (int r = 0; r < 16; ++r) {
        int dd = (r & 3) + 8 * (r >> 2) + 4 * g;
        int qsw = (lo32 & 7) << 2;
        Oe[(lo32 * 64 + dd) ^ qsw] = o0[r] * inv;
        Oe[(lo32 * 64 + 32 + dd) ^ qsw] = o1[r] * inv;
    }
#pragma unroll
    for (int rep = 0; rep < 8; ++rep) {
        int idx = lane + rep * 64;
        int qq = idx >> 4, d4 = idx & 15;
        f32x4 ov = *(const f32x4*)&Oe[(qq * 64 + d4 * 4) ^ ((qq & 7) << 2)];
        short4v pk4 = {(short)bf16rn(ov.x), (short)bf16rn(ov.y),
                       (short)bf16rn(ov.z), (short)bf16rn(ov.w)};
        *(short4v*)(ctxb + ((size_t)b * S_ + s0 + wv * 32 + qq) * D_ + h * 64 + d4 * 4) = pk4;
    }
}

// ---------------------------------------------------------------------------
// outproj: Out[m,n] = sum_k ctx[m,k] * Wo[n,k] + bo[n], bf16 MFMA.
// grid (16 n-tiles, 32 m-tiles), block 128 (2 waves x 64m x 64n). BK=128.
// ---------------------------------------------------------------------------
__global__ __launch_bounds__(128, 2) void outproj_kernel(
    const ushort_t* __restrict__ ctxb, const ushort_t* __restrict__ wob,
    const float* __restrict__ bo, float* __restrict__ Out)
{
    __shared__ __align__(16) ushort_t Cs[128 * 128];
    __shared__ __align__(16) ushort_t Ws2[64 * 128];
    const int tid = threadIdx.x;
    const int wv = tid >> 6, lane = tid & 63;
    const int lo32 = lane & 31, g = lane >> 5;
    const int n0 = blockIdx.x * 64;
    const int m0 = blockIdx.y * 128;
    f32x16 a00 = Z16, a01 = Z16, a10 = Z16, a11 = Z16;
    for (int k0 = 0; k0 < D_; k0 += 128) {
        __syncthreads();
#pragma unroll
        for (int u = 0; u < 16; ++u) {
            int idx = tid + u * 128;
            int m = idx >> 4, c8 = idx & 15;
            short8 cv = *(const short8*)(ctxb + (size_t)(m0 + m) * D_ + k0 + c8 * 8);
            *(short8*)&Cs[(m * 128 + c8 * 8) ^ ((m & 15) << 3)] = cv;
        }
#pragma unroll
        for (int u = 0; u < 8; ++u) {
            int idx = tid + u * 128;
            int n = idx >> 4, c8 = idx & 15;
            short8 w8 = *(const short8*)(wob + (size_t)(n0 + n) * D_ + k0 + c8 * 8);
            *(short8*)&Ws2[(n * 128 + c8 * 8) ^ ((n & 15) << 3)] = w8;
        }
        __syncthreads();
#pragma unroll
        for (int ks = 0; ks < 8; ++ks) {
            int coff = ks * 16 + g * 8;
            int r0 = wv * 64 + lo32, r1 = r0 + 32;
            int n1 = lo32 + 32;
            short8 A0 = *(const short8*)&Cs[(r0 * 128 + coff) ^ ((r0 & 15) << 3)];
            short8 A1 = *(const short8*)&Cs[(r1 * 128 + coff) ^ ((r1 & 15) << 3)];
            short8 B0 = *(const short8*)&Ws2[(lo32 * 128 + coff) ^ ((lo32 & 15) << 3)];
            short8 B1 = *(const short8*)&Ws2[(n1 * 128 + coff) ^ ((n1 & 15) << 3)];
            a00 = MFMA(A0, B0, a00);
            a01 = MFMA(A0, B1, a01);
            a10 = MFMA(A1, B0, a10);
            a11 = MFMA(A1, B1, a11);
        }
    }
    float b0v = bo[n0 + lo32], b1v = bo[n0 + 32 + lo32];
#define OUT_STORE(ACC, MT, NT, BV)                                          \
    _Pragma("unroll")                                                       \
    for (int r = 0; r < 16; ++r) {                                          \
        int m = m0 + wv * 64 + (MT) * 32 + (r & 3) + 8 * (r >> 2) + 4 * g;  \
        int n = n0 + (NT) * 32 + lo32;                                      \
        Out[(size_t)m * D_ + n] = ACC[r] + (BV);                            \
    }
    OUT_STORE(a00, 0, 0, b0v)
    OUT_STORE(a01, 0, 1, b1v)
    OUT_STORE(a10, 1, 0, b0v)
    OUT_STORE(a11, 1, 1, b1v)
#undef OUT_STORE
}

// ---------------------------------------------------------------------------
extern "C" void kernel_launch(void* const* d_in, const int* in_sizes, int n_in,
                              void* d_out, int out_size, void* d_ws,
                              size_t ws_size, hipStream_t stream)
{
    const float* q = (const float*)d_in[0];
    const float* k = (const float*)d_in[1];
    const float* v = (const float*)d_in[2];
    const float* W_q = (const float*)d_in[3];
    const float* W_k = (const float*)d_in[4];
    const float* W_v = (const float*)d_in[5];
    const float* W_o = (const float*)d_in[6];
    const float* b_o = (const float*)d_in[7];
    float* out = (float*)d_out;

    ushort_t* wqt_h = (ushort_t*)d_ws;            // [16][64][1024]
    ushort_t* wqt_l = wqt_h + (1 << 20);
    ushort_t* wkt_h = wqt_l + (1 << 20);
    ushort_t* wkt_l = wkt_h + (1 << 20);
    ushort_t* wvt_h = wkt_l + (1 << 20);
    ushort_t* wob = wvt_h + (1 << 20);            // [1024][1024]
    ushort_t* qh_h = wob + (1 << 20);             // [2][16][2048][64]
    ushort_t* qh_l = qh_h + (1 << 22);
    ushort_t* kh_h = qh_l + (1 << 22);
    ushort_t* kh_l = kh_h + (1 << 22);
    ushort_t* vhp = kh_l + (1 << 22);
    ushort_t* ctxb = vhp + (1 << 22);             // [2][2048][1024]

    cvtw_kernel<<<dim3(16, 16, 3), 256, 0, stream>>>(
        W_q, W_k, W_v, wqt_h, wqt_l, wkt_h, wkt_l, wvt_h);
    cvtwo_kernel<<<1024, 256, 0, stream>>>(W_o, wob);
    proj_kernel<<<dim3(16, 16, 6), 128, 0, stream>>>(
        q, k, v, wqt_h, wqt_l, wkt_h, wkt_l, wvt_h,
        qh_h, qh_l, kh_h, kh_l, vhp);
    attn_kernel<<<dim3(16, 16, 2), 256, 0, stream>>>(
        qh_h, qh_l, kh_h, kh_l, vhp, ctxb);
    outproj_kernel<<<dim3(16, 32), 128, 0, stream>>>(ctxb, wob, b_o, out);
}

// Round 4
// 272.708 us; speedup vs baseline: 4.7594x; 1.0906x over previous
//
#include <hip/hip_runtime.h>
#include <math.h>

#define B_ 2
#define S_ 2048
#define D_ 1024
#define H_ 16
#define ATTN_C 0.18033688011f   // log2(e)/8  (fold 1/sqrt(64) into exp2)

typedef unsigned short ushort_t;
typedef __attribute__((ext_vector_type(8))) short short8;
typedef __attribute__((ext_vector_type(4))) short short4v;
typedef __attribute__((ext_vector_type(4))) float f32x4;
typedef __attribute__((ext_vector_type(16))) float f32x16;
typedef __attribute__((ext_vector_type(4))) unsigned int uint4v;

#define MFMA(A, B, C) __builtin_amdgcn_mfma_f32_32x32x16_bf16((A), (B), (C), 0, 0, 0)
#define Z16 {0.f,0.f,0.f,0.f,0.f,0.f,0.f,0.f,0.f,0.f,0.f,0.f,0.f,0.f,0.f,0.f}

__device__ __forceinline__ ushort_t bf16rn(float x) {
    unsigned int u = __builtin_bit_cast(unsigned int, x);
    u += 0x7FFFu + ((u >> 16) & 1u);
    return (ushort_t)(u >> 16);
}
__device__ __forceinline__ float bf16tof(ushort_t h) {
    return __builtin_bit_cast(float, (unsigned int)h << 16);
}
__device__ __forceinline__ unsigned cvtpk(float lo, float hi) {
    unsigned r;
    asm("v_cvt_pk_bf16_f32 %0, %1, %2" : "=v"(r) : "v"(lo), "v"(hi));
    return r;
}

// ---------------------------------------------------------------------------
// cvtx: X (q|k|v) fp32 -> hi bf16 plane (+ lo plane for q,k).
// Layout: Xh[(pr*2+b)*S + s][d], Xl[(pr*2+b)*S + s][d] (pr<2 only).
// grid (2048, 3), block 256, 8 elems/thread.
// ---------------------------------------------------------------------------
__global__ __launch_bounds__(256) void cvtx_kernel(
    const float* __restrict__ Xq, const float* __restrict__ Xk,
    const float* __restrict__ Xv,
    ushort_t* __restrict__ Xh, ushort_t* __restrict__ Xl)
{
    const int pr = blockIdx.y;
    const float* X = pr == 0 ? Xq : pr == 1 ? Xk : Xv;
    const size_t idx = ((size_t)blockIdx.x * 256 + threadIdx.x) * 8;
    f32x4 v0 = *(const f32x4*)(X + idx);
    f32x4 v1 = *(const f32x4*)(X + idx + 4);
    float f[8] = {v0.x, v0.y, v0.z, v0.w, v1.x, v1.y, v1.z, v1.w};
    short8 hi, lo;
#pragma unroll
    for (int i = 0; i < 8; ++i) {
        ushort_t hh = bf16rn(f[i]);
        hi[i] = (short)hh;
        lo[i] = (short)bf16rn(f[i] - bf16tof(hh));
    }
    const size_t base = (size_t)pr * 2 * S_ * D_;
    *(short8*)(Xh + base + idx) = hi;
    if (pr < 2) *(short8*)(Xl + base + idx) = lo;
}

// ---------------------------------------------------------------------------
// cvtw: W_q/W_k -> transposed hi/lo bf16 [h][n][1024]; W_v -> transposed hi.
// grid (16 dtiles, 16 h, 3 mat), block 256.
// ---------------------------------------------------------------------------
__global__ __launch_bounds__(256) void cvtw_kernel(
    const float* __restrict__ Wq, const float* __restrict__ Wk,
    const float* __restrict__ Wv,
    ushort_t* __restrict__ wqh, ushort_t* __restrict__ wql,
    ushort_t* __restrict__ wkh, ushort_t* __restrict__ wkl,
    ushort_t* __restrict__ wvh)
{
    __shared__ float T[64][68];
    const int dt = blockIdx.x, h = blockIdx.y, mat = blockIdx.z;
    const int tid = threadIdx.x;
    const float* W = mat == 0 ? Wq : mat == 1 ? Wk : Wv;
    const float* Wb = W + ((size_t)h * 1024 + dt * 64) * 64;
#pragma unroll
    for (int u = 0; u < 4; ++u) {
        int idx = tid + u * 256;
        int d = idx >> 4, c4 = idx & 15;
        f32x4 v = *(const f32x4*)(Wb + (size_t)d * 64 + c4 * 4);
        T[d][c4 * 4 + 0] = v.x; T[d][c4 * 4 + 1] = v.y;
        T[d][c4 * 4 + 2] = v.z; T[d][c4 * 4 + 3] = v.w;
    }
    __syncthreads();
    ushort_t* oh = mat == 0 ? wqh : mat == 1 ? wkh : wvh;
    ushort_t* ol = mat == 0 ? wql : mat == 1 ? wkl : nullptr;
#pragma unroll
    for (int u = 0; u < 4; ++u) {
        int idx = tid + u * 256;
        int n = idx >> 4, c4 = idx & 15;
        float v0 = T[c4 * 4 + 0][n], v1 = T[c4 * 4 + 1][n];
        float v2 = T[c4 * 4 + 2][n], v3 = T[c4 * 4 + 3][n];
        ushort_t h0 = bf16rn(v0), h1 = bf16rn(v1), h2 = bf16rn(v2), h3 = bf16rn(v3);
        size_t off = ((size_t)h * 64 + n) * 1024 + dt * 64 + c4 * 4;
        short4v hv = {(short)h0, (short)h1, (short)h2, (short)h3};
        *(short4v*)(oh + off) = hv;
        if (ol) {
            short4v lv = {(short)bf16rn(v0 - bf16tof(h0)), (short)bf16rn(v1 - bf16tof(h1)),
                          (short)bf16rn(v2 - bf16tof(h2)), (short)bf16rn(v3 - bf16tof(h3))};
            *(short4v*)(ol + off) = lv;
        }
    }
}

// W_o fp32 -> bf16 copy
__global__ __launch_bounds__(256) void cvtwo_kernel(
    const float* __restrict__ Wo, ushort_t* __restrict__ wob)
{
    size_t idx = (size_t)blockIdx.x * 256 + threadIdx.x;
    f32x4 v = *(const f32x4*)(Wo + idx * 4);
    short4v o = {(short)bf16rn(v.x), (short)bf16rn(v.y),
                 (short)bf16rn(v.z), (short)bf16rn(v.w)};
    *(short4v*)(wob + idx * 4) = o;
}

// ---------------------------------------------------------------------------
// proj: Out[b,h,s,n] = sum_d X[b,s,d] * W[h,d,n].  Pre-converted bf16 hi/lo
// inputs; pure ds_read+MFMA inner loop.  Q/K: split-3.  V: single.
// grid (16 m-tiles, 8 n-tiles of 128 head-major cols, pr*2+b), block 256
// (4 waves 2x2, each 64x64).  BK=64.
// ---------------------------------------------------------------------------
__global__ __launch_bounds__(256, 2) void proj_kernel(
    const ushort_t* __restrict__ Xh, const ushort_t* __restrict__ Xl,
    const ushort_t* __restrict__ Wh_q, const ushort_t* __restrict__ Wl_q,
    const ushort_t* __restrict__ Wh_k, const ushort_t* __restrict__ Wl_k,
    const ushort_t* __restrict__ Wh_v,
    ushort_t* __restrict__ Oq_h, ushort_t* __restrict__ Oq_l,
    ushort_t* __restrict__ Ok_h, ushort_t* __restrict__ Ok_l,
    ushort_t* __restrict__ Ov)
{
    __shared__ __align__(16) ushort_t Xs[128 * 128];  // [s][half*64+d] ^ ((s&15)<<3)
    __shared__ __align__(16) ushort_t Ws[128 * 128];  // [n][half*64+d] ^ ((n&15)<<3)
    const int tid = threadIdx.x;
    const int wv = tid >> 6, lane = tid & 63;
    const int lo32 = lane & 31, g = lane >> 5;
    const int wm = wv >> 1, wn = wv & 1;
    const int m0 = blockIdx.x * 128;
    const int n0 = blockIdx.y * 128;
    const int pr = blockIdx.z >> 1, b = blockIdx.z & 1;
    const bool split = (pr != 2);
    const ushort_t* Whp = pr == 0 ? Wh_q : pr == 1 ? Wh_k : Wh_v;
    const ushort_t* Wlp = pr == 0 ? Wl_q : pr == 1 ? Wl_k : Wh_v;
    const ushort_t* Xhb = Xh + ((size_t)(pr * 2 + b) * S_ + m0) * D_;
    const ushort_t* Xlb = Xl + ((size_t)(pr * 2 + b) * S_ + m0) * D_;
    f32x16 a00 = Z16, a01 = Z16, a10 = Z16, a11 = Z16;

    for (int d0 = 0; d0 < D_; d0 += 64) {
        __syncthreads();
        // stage X tile: idx -> row (128), half (hi/lo), chunk
#pragma unroll
        for (int u = 0; u < 8; ++u) {
            int idx = tid + u * 256;
            int row = idx >> 4, qq = idx & 15;
            int half = qq >> 3, c8 = qq & 7;
            int dst = (row * 128 + half * 64 + c8 * 8) ^ ((row & 15) << 3);
            if (split || half == 0) {
                const ushort_t* src = (half ? Xlb : Xhb) + (size_t)row * D_ + d0 + c8 * 8;
                *(short8*)&Xs[dst] = *(const short8*)src;
            }
        }
        // stage W tile
#pragma unroll
        for (int u = 0; u < 8; ++u) {
            int idx = tid + u * 256;
            int row = idx >> 4, qq = idx & 15;
            int half = qq >> 3, c8 = qq & 7;
            int dst = (row * 128 + half * 64 + c8 * 8) ^ ((row & 15) << 3);
            if (split || half == 0) {
                const ushort_t* src = (half ? Wlp : Whp) + (size_t)(n0 + row) * 1024 + d0 + c8 * 8;
                *(short8*)&Ws[dst] = *(const short8*)src;
            }
        }
        __syncthreads();
#pragma unroll
        for (int ks = 0; ks < 4; ++ks) {
            int coff = ks * 16 + g * 8;
            int r0 = wm * 64 + lo32, r1 = r0 + 32;
            int c0 = wn * 64 + lo32, c1 = c0 + 32;
            short8 a0h = *(const short8*)&Xs[(r0 * 128 + coff) ^ ((r0 & 15) << 3)];
            short8 a1h = *(const short8*)&Xs[(r1 * 128 + coff) ^ ((r1 & 15) << 3)];
            short8 b0h = *(const short8*)&Ws[(c0 * 128 + coff) ^ ((c0 & 15) << 3)];
            short8 b1h = *(const short8*)&Ws[(c1 * 128 + coff) ^ ((c1 & 15) << 3)];
            a00 = MFMA(a0h, b0h, a00);
            a01 = MFMA(a0h, b1h, a01);
            a10 = MFMA(a1h, b0h, a10);
            a11 = MFMA(a1h, b1h, a11);
            if (split) {
                short8 a0l = *(const short8*)&Xs[(r0 * 128 + 64 + coff) ^ ((r0 & 15) << 3)];
                short8 a1l = *(const short8*)&Xs[(r1 * 128 + 64 + coff) ^ ((r1 & 15) << 3)];
                short8 b0l = *(const short8*)&Ws[(c0 * 128 + 64 + coff) ^ ((c0 & 15) << 3)];
                short8 b1l = *(const short8*)&Ws[(c1 * 128 + 64 + coff) ^ ((c1 & 15) << 3)];
                a00 = MFMA(a0h, b0l, a00); a00 = MFMA(a0l, b0h, a00);
                a01 = MFMA(a0h, b1l, a01); a01 = MFMA(a0l, b1h, a01);
                a10 = MFMA(a1h, b0l, a10); a10 = MFMA(a1l, b0h, a10);
                a11 = MFMA(a1h, b1l, a11); a11 = MFMA(a1l, b1h, a11);
            }
        }
    }
    ushort_t* OH = pr == 0 ? Oq_h : pr == 1 ? Ok_h : Ov;
    ushort_t* OL = pr == 0 ? Oq_l : pr == 1 ? Ok_l : Ov;
#define PROJ_STORE(ACC, MT, NT)                                               \
    _Pragma("unroll")                                                         \
    for (int r = 0; r < 16; ++r) {                                            \
        int s_loc = m0 + wm * 64 + (MT) * 32 + (r & 3) + 8 * (r >> 2) + 4 * g;\
        int col = n0 + wn * 64 + (NT) * 32 + lo32;                            \
        int hh_ = col >> 6, nn = col & 63;                                    \
        float val = ACC[r];                                                   \
        size_t off = (((size_t)b * H_ + hh_) * S_ + s_loc) * 64 + nn;         \
        if (split) {                                                          \
            ushort_t hv = bf16rn(val);                                        \
            OH[off] = hv;                                                     \
            OL[off] = bf16rn(val - bf16tof(hv));                              \
        } else OH[off] = bf16rn(val);                                         \
    }
    PROJ_STORE(a00, 0, 0)
    PROJ_STORE(a01, 0, 1)
    PROJ_STORE(a10, 1, 0)
    PROJ_STORE(a11, 1, 1)
#undef PROJ_STORE
}

// ---------------------------------------------------------------------------
// attn: swapped QK^T (S^T = mfma(K,Q)), per-lane online softmax, P via
// cvt_pk + shfl_xor(32), O^T = mfma(Vt,P).  (unchanged from round 3)
// ---------------------------------------------------------------------------
__global__ __launch_bounds__(256, 2) void attn_kernel(
    const ushort_t* __restrict__ qh_h, const ushort_t* __restrict__ qh_l,
    const ushort_t* __restrict__ kh_h, const ushort_t* __restrict__ kh_l,
    const ushort_t* __restrict__ vh, ushort_t* __restrict__ ctxb)
{
    __shared__ __align__(16) ushort_t Ks[64 * 128];
    __shared__ __align__(16) ushort_t Vt[64 * 64];
    __shared__ __align__(16) float Oep[4 * 32 * 64];
    const int tid = threadIdx.x;
    const int wv = tid >> 6, lane = tid & 63;
    const int lo32 = lane & 31, g = lane >> 5;
    const int s0 = blockIdx.x * 128;
    const int h = blockIdx.y, b = blockIdx.z;
    const size_t bhs = ((size_t)b * H_ + h) * S_ * 64;

    const ushort_t* Qrh = qh_h + bhs + (size_t)(s0 + wv * 32 + lo32) * 64;
    const ushort_t* Qrl = qh_l + bhs + (size_t)(s0 + wv * 32 + lo32) * 64;
    short8 qfh[4], qfl[4];
#pragma unroll
    for (int ks = 0; ks < 4; ++ks) {
        qfh[ks] = *(const short8*)(Qrh + ks * 16 + g * 8);
        qfl[ks] = *(const short8*)(Qrl + ks * 16 + g * 8);
    }
    const ushort_t* Kgh = kh_h + bhs;
    const ushort_t* Kgl = kh_l + bhs;
    const ushort_t* Vg = vh + bhs;

    f32x16 o0 = Z16, o1 = Z16;
    float mrun = -3.0e38f, lrun = 0.0f;

    for (int kv0 = 0; kv0 < S_; kv0 += 64) {
        __syncthreads();
#pragma unroll
        for (int rep = 0; rep < 2; ++rep) {
            int idx = tid + rep * 256;
            int row = idx >> 3, c8 = idx & 7;
            short8 ah = *(const short8*)(Kgh + (size_t)(kv0 + row) * 64 + c8 * 8);
            short8 al = *(const short8*)(Kgl + (size_t)(kv0 + row) * 64 + c8 * 8);
            int sw = (row & 15) << 3;
            *(short8*)&Ks[(row * 128 + c8 * 8) ^ sw] = ah;
            *(short8*)&Ks[(row * 128 + 64 + c8 * 8) ^ sw] = al;
        }
        {
            int kvp = tid & 31, d8 = tid >> 5;
            const ushort_t* vp = Vg + (size_t)(kv0 + 2 * kvp) * 64 + d8 * 8;
            short8 va = *(const short8*)(vp);
            short8 vb = *(const short8*)(vp + 64);
#pragma unroll
            for (int i = 0; i < 8; ++i) {
                int d = d8 * 8 + i;
                unsigned wrd = ((unsigned)(ushort_t)vb[i] << 16) | (ushort_t)va[i];
                *(unsigned*)&Vt[(d * 64 + 2 * kvp) ^ ((d & 7) << 3)] = wrd;
            }
        }
        __syncthreads();
#pragma unroll
        for (int ch = 0; ch < 2; ++ch) {
            int kvb = ch * 32;
            f32x16 st = Z16;
#pragma unroll
            for (int ks = 0; ks < 4; ++ks) {
                int krow = kvb + lo32;
                int base = krow * 128 + ks * 16 + g * 8;
                int sw = (krow & 15) << 3;
                short8 kfh = *(const short8*)&Ks[base ^ sw];
                short8 kfl = *(const short8*)&Ks[(base + 64) ^ sw];
                st = MFMA(kfh, qfh[ks], st);
                st = MFMA(kfh, qfl[ks], st);
                st = MFMA(kfl, qfh[ks], st);
            }
            float cmax = st[0];
#pragma unroll
            for (int r = 1; r < 16; ++r) cmax = fmaxf(cmax, st[r]);
            cmax = fmaxf(cmax, __shfl_xor(cmax, 32));
            float mnew = fmaxf(mrun, cmax);
            float corr = exp2f((mrun - mnew) * ATTN_C);
            float p[16];
            float ls = 0.f;
#pragma unroll
            for (int r = 0; r < 16; ++r) {
                p[r] = exp2f((st[r] - mnew) * ATTN_C);
                ls += p[r];
            }
            lrun = lrun * corr + ls;
#pragma unroll
            for (int r = 0; r < 16; ++r) { o0[r] *= corr; o1[r] *= corr; }
            mrun = mnew;
#pragma unroll
            for (int ks2 = 0; ks2 < 2; ++ks2) {
                int rr = ks2 * 8;
                unsigned w0 = cvtpk(p[rr + 0], p[rr + 1]);
                unsigned w1 = cvtpk(p[rr + 2], p[rr + 3]);
                unsigned w2 = cvtpk(p[rr + 4], p[rr + 5]);
                unsigned w3 = cvtpk(p[rr + 6], p[rr + 7]);
                unsigned x0 = (unsigned)__shfl_xor((int)w0, 32);
                unsigned x1 = (unsigned)__shfl_xor((int)w1, 32);
                unsigned x2 = (unsigned)__shfl_xor((int)w2, 32);
                unsigned x3 = (unsigned)__shfl_xor((int)w3, 32);
                uint4v pw = {g ? x2 : w0, g ? x3 : w1, g ? w2 : x0, g ? w3 : x1};
                short8 pfrag = __builtin_bit_cast(short8, pw);
                int kvf = kvb + ks2 * 16 + g * 8;
                int vsw = (lo32 & 7) << 3;
                short8 vf0 = *(const short8*)&Vt[(lo32 * 64 + kvf) ^ vsw];
                short8 vf1 = *(const short8*)&Vt[((lo32 + 32) * 64 + kvf) ^ vsw];
                o0 = MFMA(vf0, pfrag, o0);
                o1 = MFMA(vf1, pfrag, o1);
            }
        }
    }
    lrun += __shfl_xor(lrun, 32);
    float inv = 1.0f / lrun;
    float* Oe = Oep + wv * 2048;
#pragma unroll
    for (int r = 0; r < 16; ++r) {
        int dd = (r & 3) + 8 * (r >> 2) + 4 * g;
        int qsw = (lo32 & 7) << 2;
        Oe[(lo32 * 64 + dd) ^ qsw] = o0[r] * inv;
        Oe[(lo32 * 64 + 32 + dd) ^ qsw] = o1[r] * inv;
    }
#pragma unroll
    for (int rep = 0; rep < 8; ++rep) {
        int idx = lane + rep * 64;
        int qq = idx >> 4, d4 = idx & 15;
        f32x4 ov = *(const f32x4*)&Oe[(qq * 64 + d4 * 4) ^ ((qq & 7) << 2)];
        short4v pk4 = {(short)bf16rn(ov.x), (short)bf16rn(ov.y),
                       (short)bf16rn(ov.z), (short)bf16rn(ov.w)};
        *(short4v*)(ctxb + ((size_t)b * S_ + s0 + wv * 32 + qq) * D_ + h * 64 + d4 * 4) = pk4;
    }
}

// ---------------------------------------------------------------------------
// outproj: Out[m,n] = sum_k ctx[m,k] * Wo[n,k] + bo[n], bf16 MFMA.
// ---------------------------------------------------------------------------
__global__ __launch_bounds__(128, 2) void outproj_kernel(
    const ushort_t* __restrict__ ctxb, const ushort_t* __restrict__ wob,
    const float* __restrict__ bo, float* __restrict__ Out)
{
    __shared__ __align__(16) ushort_t Cs[128 * 128];
    __shared__ __align__(16) ushort_t Ws2[64 * 128];
    const int tid = threadIdx.x;
    const int wv = tid >> 6, lane = tid & 63;
    const int lo32 = lane & 31, g = lane >> 5;
    const int n0 = blockIdx.x * 64;
    const int m0 = blockIdx.y * 128;
    f32x16 a00 = Z16, a01 = Z16, a10 = Z16, a11 = Z16;
    for (int k0 = 0; k0 < D_; k0 += 128) {
        __syncthreads();
#pragma unroll
        for (int u = 0; u < 16; ++u) {
            int idx = tid + u * 128;
            int m = idx >> 4, c8 = idx & 15;
            short8 cv = *(const short8*)(ctxb + (size_t)(m0 + m) * D_ + k0 + c8 * 8);
            *(short8*)&Cs[(m * 128 + c8 * 8) ^ ((m & 15) << 3)] = cv;
        }
#pragma unroll
        for (int u = 0; u < 8; ++u) {
            int idx = tid + u * 128;
            int n = idx >> 4, c8 = idx & 15;
            short8 w8 = *(const short8*)(wob + (size_t)(n0 + n) * D_ + k0 + c8 * 8);
            *(short8*)&Ws2[(n * 128 + c8 * 8) ^ ((n & 15) << 3)] = w8;
        }
        __syncthreads();
#pragma unroll
        for (int ks = 0; ks < 8; ++ks) {
            int coff = ks * 16 + g * 8;
            int r0 = wv * 64 + lo32, r1 = r0 + 32;
            int n1 = lo32 + 32;
            short8 A0 = *(const short8*)&Cs[(r0 * 128 + coff) ^ ((r0 & 15) << 3)];
            short8 A1 = *(const short8*)&Cs[(r1 * 128 + coff) ^ ((r1 & 15) << 3)];
            short8 B0 = *(const short8*)&Ws2[(lo32 * 128 + coff) ^ ((lo32 & 15) << 3)];
            short8 B1 = *(const short8*)&Ws2[(n1 * 128 + coff) ^ ((n1 & 15) << 3)];
            a00 = MFMA(A0, B0, a00);
            a01 = MFMA(A0, B1, a01);
            a10 = MFMA(A1, B0, a10);
            a11 = MFMA(A1, B1, a11);
        }
    }
    float b0v = bo[n0 + lo32], b1v = bo[n0 + 32 + lo32];
#define OUT_STORE(ACC, MT, NT, BV)                                          \
    _Pragma("unroll")                                                       \
    for (int r = 0; r < 16; ++r) {                                          \
        int m = m0 + wv * 64 + (MT) * 32 + (r & 3) + 8 * (r >> 2) + 4 * g;  \
        int n = n0 + (NT) * 32 + lo32;                                      \
        Out[(size_t)m * D_ + n] = ACC[r] + (BV);                            \
    }
    OUT_STORE(a00, 0, 0, b0v)
    OUT_STORE(a01, 0, 1, b1v)
    OUT_STORE(a10, 1, 0, b0v)
    OUT_STORE(a11, 1, 1, b1v)
#undef OUT_STORE
}

// ---------------------------------------------------------------------------
extern "C" void kernel_launch(void* const* d_in, const int* in_sizes, int n_in,
                              void* d_out, int out_size, void* d_ws,
                              size_t ws_size, hipStream_t stream)
{
    const float* q = (const float*)d_in[0];
    const float* k = (const float*)d_in[1];
    const float* v = (const float*)d_in[2];
    const float* W_q = (const float*)d_in[3];
    const float* W_k = (const float*)d_in[4];
    const float* W_v = (const float*)d_in[5];
    const float* W_o = (const float*)d_in[6];
    const float* b_o = (const float*)d_in[7];
    float* out = (float*)d_out;

    // workspace layout (ushort units); total 92 MiB, ctxb aliases Xh.
    ushort_t* wqt_h = (ushort_t*)d_ws;                 // 5 x 1M: W hi/lo
    ushort_t* wqt_l = wqt_h + (1 << 20);
    ushort_t* wkt_h = wqt_l + (1 << 20);
    ushort_t* wkt_l = wkt_h + (1 << 20);
    ushort_t* wvt_h = wkt_l + (1 << 20);
    ushort_t* wob   = wvt_h + (1 << 20);               // 1M
    ushort_t* qh_h  = wob + (1 << 20);                 // 5 x 4M: proj outputs
    ushort_t* qh_l  = qh_h + (1 << 22);
    ushort_t* kh_h  = qh_l + (1 << 22);
    ushort_t* kh_l  = kh_h + (1 << 22);
    ushort_t* vhp   = kh_l + (1 << 22);
    ushort_t* Xh    = vhp + (1 << 22);                 // 12M: [3][2][S][D] hi
    ushort_t* Xl    = Xh + 3 * (1 << 22);              // 8M:  [2][2][S][D] lo
    ushort_t* ctxb  = Xh;                              // alias (Xh dead after proj)

    cvtx_kernel<<<dim3(2048, 3), 256, 0, stream>>>(q, k, v, Xh, Xl);
    cvtw_kernel<<<dim3(16, 16, 3), 256, 0, stream>>>(
        W_q, W_k, W_v, wqt_h, wqt_l, wkt_h, wkt_l, wvt_h);
    cvtwo_kernel<<<1024, 256, 0, stream>>>(W_o, wob);
    proj_kernel<<<dim3(16, 8, 6), 256, 0, stream>>>(
        Xh, Xl, wqt_h, wqt_l, wkt_h, wkt_l, wvt_h,
        qh_h, qh_l, kh_h, kh_l, vhp);
    attn_kernel<<<dim3(16, 16, 2), 256, 0, stream>>>(
        qh_h, qh_l, kh_h, kh_l, vhp, ctxb);
    outproj_kernel<<<dim3(16, 32), 128, 0, stream>>>(ctxb, wob, b_o, out);
}

// Round 5
// 224.345 us; speedup vs baseline: 5.7854x; 1.2156x over previous
//
#include <hip/hip_runtime.h>
#include <math.h>

#define B_ 2
#define S_ 2048
#define D_ 1024
#define H_ 16
#define ATTN_C 0.18033688011f   // log2(e)/8, folded into Q at proj store

typedef unsigned short ushort_t;
typedef __attribute__((ext_vector_type(8))) short short8;
typedef __attribute__((ext_vector_type(4))) short short4v;
typedef __attribute__((ext_vector_type(4))) float f32x4;
typedef __attribute__((ext_vector_type(2))) float f32x2;
typedef __attribute__((ext_vector_type(16))) float f32x16;
typedef __attribute__((ext_vector_type(4))) unsigned int uint4v;

#define MFMA(A, B, C) __builtin_amdgcn_mfma_f32_32x32x16_bf16((A), (B), (C), 0, 0, 0)
#define Z16 {0.f,0.f,0.f,0.f,0.f,0.f,0.f,0.f,0.f,0.f,0.f,0.f,0.f,0.f,0.f,0.f}

__device__ __forceinline__ ushort_t bf16rn(float x) {
    unsigned int u = __builtin_bit_cast(unsigned int, x);
    u += 0x7FFFu + ((u >> 16) & 1u);
    return (ushort_t)(u >> 16);
}
__device__ __forceinline__ float bf16tof(ushort_t h) {
    return __builtin_bit_cast(float, (unsigned int)h << 16);
}
__device__ __forceinline__ unsigned cvtpk(float lo, float hi) {
    unsigned r;
    asm("v_cvt_pk_bf16_f32 %0, %1, %2" : "=v"(r) : "v"(lo), "v"(hi));
    return r;
}
// global -> LDS direct 16B load: per-lane global src, wave-uniform LDS base,
// HW writes base + lane*16 (CK-style addrspace casts).
__device__ __forceinline__ void gload16(const void* g, void* l) {
    __builtin_amdgcn_global_load_lds(
        (const __attribute__((address_space(1))) unsigned int*)(unsigned long long)g,
        (__attribute__((address_space(3))) unsigned int*)(unsigned int)(unsigned long long)l,
        16, 0, 0);
}

// ---------------------------------------------------------------------------
// cvtx: X (q|k|v) fp32 -> hi bf16 plane (+ lo plane for q,k).
// ---------------------------------------------------------------------------
__global__ __launch_bounds__(256) void cvtx_kernel(
    const float* __restrict__ Xq, const float* __restrict__ Xk,
    const float* __restrict__ Xv,
    ushort_t* __restrict__ Xh, ushort_t* __restrict__ Xl)
{
    const int pr = blockIdx.y;
    const float* X = pr == 0 ? Xq : pr == 1 ? Xk : Xv;
    const size_t idx = ((size_t)blockIdx.x * 256 + threadIdx.x) * 8;
    f32x4 v0 = *(const f32x4*)(X + idx);
    f32x4 v1 = *(const f32x4*)(X + idx + 4);
    float f[8] = {v0.x, v0.y, v0.z, v0.w, v1.x, v1.y, v1.z, v1.w};
    short8 hi, lo;
#pragma unroll
    for (int i = 0; i < 8; ++i) {
        ushort_t hh = bf16rn(f[i]);
        hi[i] = (short)hh;
        lo[i] = (short)bf16rn(f[i] - bf16tof(hh));
    }
    const size_t base = (size_t)pr * 2 * S_ * D_;
    *(short8*)(Xh + base + idx) = hi;
    if (pr < 2) *(short8*)(Xl + base + idx) = lo;
}

// ---------------------------------------------------------------------------
// cvtw: W_q/W_k -> transposed hi/lo bf16 [h][n][1024]; W_v -> transposed hi.
// ---------------------------------------------------------------------------
__global__ __launch_bounds__(256) void cvtw_kernel(
    const float* __restrict__ Wq, const float* __restrict__ Wk,
    const float* __restrict__ Wv,
    ushort_t* __restrict__ wqh, ushort_t* __restrict__ wql,
    ushort_t* __restrict__ wkh, ushort_t* __restrict__ wkl,
    ushort_t* __restrict__ wvh)
{
    __shared__ float T[64][68];
    const int dt = blockIdx.x, h = blockIdx.y, mat = blockIdx.z;
    const int tid = threadIdx.x;
    const float* W = mat == 0 ? Wq : mat == 1 ? Wk : Wv;
    const float* Wb = W + ((size_t)h * 1024 + dt * 64) * 64;
#pragma unroll
    for (int u = 0; u < 4; ++u) {
        int idx = tid + u * 256;
        int d = idx >> 4, c4 = idx & 15;
        f32x4 v = *(const f32x4*)(Wb + (size_t)d * 64 + c4 * 4);
        T[d][c4 * 4 + 0] = v.x; T[d][c4 * 4 + 1] = v.y;
        T[d][c4 * 4 + 2] = v.z; T[d][c4 * 4 + 3] = v.w;
    }
    __syncthreads();
    ushort_t* oh = mat == 0 ? wqh : mat == 1 ? wkh : wvh;
    ushort_t* ol = mat == 0 ? wql : mat == 1 ? wkl : nullptr;
#pragma unroll
    for (int u = 0; u < 4; ++u) {
        int idx = tid + u * 256;
        int n = idx >> 4, c4 = idx & 15;
        float v0 = T[c4 * 4 + 0][n], v1 = T[c4 * 4 + 1][n];
        float v2 = T[c4 * 4 + 2][n], v3 = T[c4 * 4 + 3][n];
        ushort_t h0 = bf16rn(v0), h1 = bf16rn(v1), h2 = bf16rn(v2), h3 = bf16rn(v3);
        size_t off = ((size_t)h * 64 + n) * 1024 + dt * 64 + c4 * 4;
        short4v hv = {(short)h0, (short)h1, (short)h2, (short)h3};
        *(short4v*)(oh + off) = hv;
        if (ol) {
            short4v lv = {(short)bf16rn(v0 - bf16tof(h0)), (short)bf16rn(v1 - bf16tof(h1)),
                          (short)bf16rn(v2 - bf16tof(h2)), (short)bf16rn(v3 - bf16tof(h3))};
            *(short4v*)(ol + off) = lv;
        }
    }
}

__global__ __launch_bounds__(256) void cvtwo_kernel(
    const float* __restrict__ Wo, ushort_t* __restrict__ wob)
{
    size_t idx = (size_t)blockIdx.x * 256 + threadIdx.x;
    f32x4 v = *(const f32x4*)(Wo + idx * 4);
    short4v o = {(short)bf16rn(v.x), (short)bf16rn(v.y),
                 (short)bf16rn(v.z), (short)bf16rn(v.w)};
    *(short4v*)(wob + idx * 4) = o;
}

// ---------------------------------------------------------------------------
// proj: Out[b,h,s,n] = sum_d X[b,s,d] * W[h,d,n].  global_load_lds staging
// with inverse-swizzled per-lane source (granule ^= row&15); Q pre-scaled by
// ATTN_C at store.  grid (16, 8, pr*2+b), block 256 (4 waves, 2x2 of 64x64).
// ---------------------------------------------------------------------------
__global__ __launch_bounds__(256, 2) void proj_kernel(
    const ushort_t* __restrict__ Xh, const ushort_t* __restrict__ Xl,
    const ushort_t* __restrict__ Wh_q, const ushort_t* __restrict__ Wl_q,
    const ushort_t* __restrict__ Wh_k, const ushort_t* __restrict__ Wl_k,
    const ushort_t* __restrict__ Wh_v,
    ushort_t* __restrict__ Oq_h, ushort_t* __restrict__ Oq_l,
    ushort_t* __restrict__ Ok_h, ushort_t* __restrict__ Ok_l,
    ushort_t* __restrict__ Ov)
{
    __shared__ __align__(16) ushort_t Xs[128 * 128];  // [row][half*64+d] ^ ((row&15)<<3)
    __shared__ __align__(16) ushort_t Ws[128 * 128];
    const int tid = threadIdx.x;
    const int wv = tid >> 6, lane = tid & 63;
    const int lo32 = lane & 31, g = lane >> 5;
    const int wm = wv >> 1, wn = wv & 1;
    const int lrow = lane >> 4, lg = lane & 15;
    const int m0 = blockIdx.x * 128;
    const int n0 = blockIdx.y * 128;
    const int pr = blockIdx.z >> 1, b = blockIdx.z & 1;
    const bool split = (pr != 2);
    const ushort_t* Whp = pr == 0 ? Wh_q : pr == 1 ? Wh_k : Wh_v;
    const ushort_t* Wlp = pr == 0 ? Wl_q : pr == 1 ? Wl_k : Wh_v;
    const ushort_t* Xhb = Xh + ((size_t)(pr * 2 + b) * S_ + m0) * D_;
    const ushort_t* Xlb = Xl + ((size_t)(pr * 2 + b) * S_ + m0) * D_;
    f32x16 a00 = Z16, a01 = Z16, a10 = Z16, a11 = Z16;

    for (int d0 = 0; d0 < D_; d0 += 64) {
        __syncthreads();
#pragma unroll
        for (int u = 0; u < 8; ++u) {
            int row = u * 16 + wv * 4 + lrow;
            int gs = lg ^ (row & 15);
            int half = gs >> 3, c8 = gs & 7;
            const ushort_t* srcX = ((half && split) ? Xlb : Xhb) + (size_t)row * D_ + d0 + c8 * 8;
            gload16(srcX, (char*)Xs + (u * 16 + wv * 4) * 256);
            const ushort_t* srcW = ((half && split) ? Wlp : Whp) + (size_t)(n0 + row) * 1024 + d0 + c8 * 8;
            gload16(srcW, (char*)Ws + (u * 16 + wv * 4) * 256);
        }
        __syncthreads();
#pragma unroll
        for (int ks = 0; ks < 4; ++ks) {
            int coff = ks * 16 + g * 8;
            int r0 = wm * 64 + lo32, r1 = r0 + 32;
            int c0 = wn * 64 + lo32, c1 = c0 + 32;
            short8 a0h = *(const short8*)&Xs[(r0 * 128 + coff) ^ ((r0 & 15) << 3)];
            short8 a1h = *(const short8*)&Xs[(r1 * 128 + coff) ^ ((r1 & 15) << 3)];
            short8 b0h = *(const short8*)&Ws[(c0 * 128 + coff) ^ ((c0 & 15) << 3)];
            short8 b1h = *(const short8*)&Ws[(c1 * 128 + coff) ^ ((c1 & 15) << 3)];
            a00 = MFMA(a0h, b0h, a00);
            a01 = MFMA(a0h, b1h, a01);
            a10 = MFMA(a1h, b0h, a10);
            a11 = MFMA(a1h, b1h, a11);
            if (split) {
                short8 a0l = *(const short8*)&Xs[(r0 * 128 + 64 + coff) ^ ((r0 & 15) << 3)];
                short8 a1l = *(const short8*)&Xs[(r1 * 128 + 64 + coff) ^ ((r1 & 15) << 3)];
                short8 b0l = *(const short8*)&Ws[(c0 * 128 + 64 + coff) ^ ((c0 & 15) << 3)];
                short8 b1l = *(const short8*)&Ws[(c1 * 128 + 64 + coff) ^ ((c1 & 15) << 3)];
                a00 = MFMA(a0h, b0l, a00); a00 = MFMA(a0l, b0h, a00);
                a01 = MFMA(a0h, b1l, a01); a01 = MFMA(a0l, b1h, a01);
                a10 = MFMA(a1h, b0l, a10); a10 = MFMA(a1l, b0h, a10);
                a11 = MFMA(a1h, b1l, a11); a11 = MFMA(a1l, b1h, a11);
            }
        }
    }
    ushort_t* OH = pr == 0 ? Oq_h : pr == 1 ? Ok_h : Ov;
    ushort_t* OL = pr == 0 ? Oq_l : pr == 1 ? Ok_l : Ov;
    const bool qscale = (pr == 0);
#define PROJ_STORE(ACC, MT, NT)                                               \
    _Pragma("unroll")                                                         \
    for (int r = 0; r < 16; ++r) {                                            \
        int s_loc = m0 + wm * 64 + (MT) * 32 + (r & 3) + 8 * (r >> 2) + 4 * g;\
        int col = n0 + wn * 64 + (NT) * 32 + lo32;                            \
        int hh_ = col >> 6, nn = col & 63;                                    \
        float val = ACC[r];                                                   \
        if (qscale) val *= ATTN_C;                                            \
        size_t off = (((size_t)b * H_ + hh_) * S_ + s_loc) * 64 + nn;         \
        if (split) {                                                          \
            ushort_t hv = bf16rn(val);                                        \
            OH[off] = hv;                                                     \
            OL[off] = bf16rn(val - bf16tof(hv));                              \
        } else OH[off] = bf16rn(val);                                         \
    }
    PROJ_STORE(a00, 0, 0)
    PROJ_STORE(a01, 0, 1)
    PROJ_STORE(a10, 1, 0)
    PROJ_STORE(a11, 1, 1)
#undef PROJ_STORE
}

// ---------------------------------------------------------------------------
// attn: split-KV flash.  grid (16 q-tiles, 16 h, b*2+split), block 256.
// Swapped QK^T, per-lane online softmax (Q pre-scaled: scores in log2 units),
// skip-rescale branch, P exchange via v_permlane32_swap_b32, O^T=mfma(Vt,P).
// Outputs unnormalized bf16 partial O + (m,l) per row; merged by merge_kernel.
// ---------------------------------------------------------------------------
__global__ __launch_bounds__(256, 4) void attn_kernel(
    const ushort_t* __restrict__ qh_h, const ushort_t* __restrict__ qh_l,
    const ushort_t* __restrict__ kh_h, const ushort_t* __restrict__ kh_l,
    const ushort_t* __restrict__ vh, ushort_t* __restrict__ Opart,
    float* __restrict__ Ml)
{
    __shared__ __align__(16) char smem[32768];
    ushort_t* Ks = (ushort_t*)smem;              // 16KB [64][128] swizzled
    ushort_t* Vt = (ushort_t*)(smem + 16384);    // 8KB  [64][64]  swizzled
    const int tid = threadIdx.x;
    const int wv = tid >> 6, lane = tid & 63;
    const int lo32 = lane & 31, g = lane >> 5;
    const int lrow = lane >> 4, lg = lane & 15;
    const int s0 = blockIdx.x * 128;
    const int h = blockIdx.y;
    const int b = blockIdx.z >> 1, sp = blockIdx.z & 1;
    const size_t bhs = ((size_t)b * H_ + h) * S_ * 64;

    const ushort_t* Qrh = qh_h + bhs + (size_t)(s0 + wv * 32 + lo32) * 64;
    const ushort_t* Qrl = qh_l + bhs + (size_t)(s0 + wv * 32 + lo32) * 64;
    short8 qfh[4], qfl[4];
#pragma unroll
    for (int ks = 0; ks < 4; ++ks) {
        qfh[ks] = *(const short8*)(Qrh + ks * 16 + g * 8);
        qfl[ks] = *(const short8*)(Qrl + ks * 16 + g * 8);
    }
    const ushort_t* Kgh = kh_h + bhs;
    const ushort_t* Kgl = kh_l + bhs;
    const ushort_t* Vg = vh + bhs;

    f32x16 o0 = Z16, o1 = Z16;
    float mrun = -3.0e38f, lrun = 0.0f;
    const int kvbeg = sp * (S_ / 2), kvend = kvbeg + (S_ / 2);

    for (int kv0 = kvbeg; kv0 < kvend; kv0 += 64) {
        __syncthreads();
        // K stage via global_load_lds (source pre-swizzled)
#pragma unroll
        for (int u = 0; u < 4; ++u) {
            int row = wv * 16 + u * 4 + lrow;
            int gs = lg ^ (row & 15);
            int half = gs >> 3, c8 = gs & 7;
            const ushort_t* src = (half ? Kgl : Kgh) + (size_t)(kv0 + row) * 64 + c8 * 8;
            gload16(src, (char*)Ks + (wv * 16 + u * 4) * 256);
        }
        // V transpose (register path)
        {
            int kvp = tid & 31, d8 = tid >> 5;
            const ushort_t* vp = Vg + (size_t)(kv0 + 2 * kvp) * 64 + d8 * 8;
            short8 va = *(const short8*)(vp);
            short8 vb = *(const short8*)(vp + 64);
#pragma unroll
            for (int i = 0; i < 8; ++i) {
                int d = d8 * 8 + i;
                unsigned wrd = ((unsigned)(ushort_t)vb[i] << 16) | (ushort_t)va[i];
                *(unsigned*)&Vt[(d * 64 + 2 * kvp) ^ ((d & 7) << 3)] = wrd;
            }
        }
        __syncthreads();
#pragma unroll
        for (int ch = 0; ch < 2; ++ch) {
            int kvb = ch * 32;
            f32x16 st = Z16;
#pragma unroll
            for (int ks = 0; ks < 4; ++ks) {
                int krow = kvb + lo32;
                int base = krow * 128 + ks * 16 + g * 8;
                int sw = (krow & 15) << 3;
                short8 kfh = *(const short8*)&Ks[base ^ sw];
                short8 kfl = *(const short8*)&Ks[(base + 64) ^ sw];
                st = MFMA(kfh, qfh[ks], st);
                st = MFMA(kfh, qfl[ks], st);
                st = MFMA(kfl, qfh[ks], st);
            }
            // column max (max3-friendly tree), pair-combine across halves
            float t0 = fmaxf(fmaxf(st[0], st[1]), st[2]);
            float t1 = fmaxf(fmaxf(st[3], st[4]), st[5]);
            float t2 = fmaxf(fmaxf(st[6], st[7]), st[8]);
            float t3 = fmaxf(fmaxf(st[9], st[10]), st[11]);
            float t4 = fmaxf(fmaxf(st[12], st[13]), st[14]);
            float cmax = fmaxf(fmaxf(fmaxf(t0, t1), t2),
                               fmaxf(fmaxf(t3, t4), st[15]));
            cmax = fmaxf(cmax, __shfl_xor(cmax, 32));
            if (!__all(cmax <= mrun)) {
                float mnew = fmaxf(mrun, cmax);
                float corr = __builtin_amdgcn_exp2f(mrun - mnew);
                lrun *= corr;
#pragma unroll
                for (int r = 0; r < 16; ++r) { o0[r] *= corr; o1[r] *= corr; }
                mrun = mnew;
            }
            float p[16];
            float ls = 0.f;
#pragma unroll
            for (int r = 0; r < 16; ++r) {
                p[r] = __builtin_amdgcn_exp2f(st[r] - mrun);
                ls += p[r];
            }
            lrun += ls;
            // P -> B-frag: cvt_pk pairs + permlane32_swap cross-half exchange
#pragma unroll
            for (int ks2 = 0; ks2 < 2; ++ks2) {
                int rr = ks2 * 8;
                unsigned w0 = cvtpk(p[rr + 0], p[rr + 1]);
                unsigned w1 = cvtpk(p[rr + 2], p[rr + 3]);
                unsigned w2 = cvtpk(p[rr + 4], p[rr + 5]);
                unsigned w3 = cvtpk(p[rr + 6], p[rr + 7]);
                asm("v_permlane32_swap_b32 %0, %1" : "+v"(w0), "+v"(w2));
                asm("v_permlane32_swap_b32 %0, %1" : "+v"(w1), "+v"(w3));
                uint4v pw = {w0, w1, w2, w3};
                short8 pfrag = __builtin_bit_cast(short8, pw);
                int kvf = kvb + ks2 * 16 + g * 8;
                int vsw = (lo32 & 7) << 3;
                short8 vf0 = *(const short8*)&Vt[(lo32 * 64 + kvf) ^ vsw];
                short8 vf1 = *(const short8*)&Vt[((lo32 + 32) * 64 + kvf) ^ vsw];
                o0 = MFMA(vf0, pfrag, o0);
                o1 = MFMA(vf1, pfrag, o1);
            }
        }
    }
    lrun += __shfl_xor(lrun, 32);
    __syncthreads();    // all waves done reading Ks/Vt before overlay reuse
    float* Oe = ((float*)smem) + wv * 2048;   // per-wave 8KB slice
#pragma unroll
    for (int r = 0; r < 16; ++r) {
        int dd = (r & 3) + 8 * (r >> 2) + 4 * g;
        int qsw = (lo32 & 7) << 2;
        Oe[(lo32 * 64 + dd) ^ qsw] = o0[r];
        Oe[(lo32 * 64 + 32 + dd) ^ qsw] = o1[r];
    }
    const size_t orow = (size_t)sp * (B_ * H_ * S_) + ((size_t)b * H_ + h) * S_ + s0 + wv * 32;
#pragma unroll
    for (int rep = 0; rep < 8; ++rep) {
        int idx = lane + rep * 64;
        int qq = idx >> 4, d4 = idx & 15;
        f32x4 ov = *(const f32x4*)&Oe[(qq * 64 + d4 * 4) ^ ((qq & 7) << 2)];
        short4v pk4 = {(short)bf16rn(ov.x), (short)bf16rn(ov.y),
                       (short)bf16rn(ov.z), (short)bf16rn(ov.w)};
        *(short4v*)(Opart + (orow + qq) * 64 + d4 * 4) = pk4;
    }
    if (g == 0) {
        f32x2 ml = {mrun, lrun};
        *(f32x2*)(Ml + (orow + lo32) * 2) = ml;
    }
}

// ---------------------------------------------------------------------------
// merge: combine 2 KV-split partials -> ctx bf16 [B,S,D].
// grid 2048, block 256; thread = (row, 8-dim chunk).
// ---------------------------------------------------------------------------
__global__ __launch_bounds__(256) void merge_kernel(
    const ushort_t* __restrict__ Opart, const float* __restrict__ Ml,
    ushort_t* __restrict__ ctxb)
{
    const int NROW = B_ * H_ * S_;
    int gidx = blockIdx.x * 256 + threadIdx.x;
    int row = gidx >> 3, d8 = (gidx & 7) * 8;
    f32x2 ml0 = *(const f32x2*)(Ml + (size_t)row * 2);
    f32x2 ml1 = *(const f32x2*)(Ml + ((size_t)NROW + row) * 2);
    float M = fmaxf(ml0.x, ml1.x);
    float w0 = __builtin_amdgcn_exp2f(ml0.x - M);
    float w1 = __builtin_amdgcn_exp2f(ml1.x - M);
    float inv = 1.f / (ml0.y * w0 + ml1.y * w1);
    w0 *= inv; w1 *= inv;
    short8 a = *(const short8*)(Opart + (size_t)row * 64 + d8);
    short8 c = *(const short8*)(Opart + ((size_t)NROW + row) * 64 + d8);
    short8 o;
#pragma unroll
    for (int i = 0; i < 8; ++i) {
        float f = bf16tof((ushort_t)a[i]) * w0 + bf16tof((ushort_t)c[i]) * w1;
        o[i] = (short)bf16rn(f);
    }
    int bb = row >> 15, hh = (row >> 11) & 15, s = row & 2047;
    *(short8*)(ctxb + ((size_t)bb * S_ + s) * D_ + hh * 64 + d8) = o;
}

// ---------------------------------------------------------------------------
// outproj: Out[m,n] = sum_k ctx[m,k]*Wo[n,k] + bo[n], bf16 MFMA,
// global_load_lds staging.  grid (16, 32), block 128 (2 waves).
// ---------------------------------------------------------------------------
__global__ __launch_bounds__(128, 2) void outproj_kernel(
    const ushort_t* __restrict__ ctxb, const ushort_t* __restrict__ wob,
    const float* __restrict__ bo, float* __restrict__ Out)
{
    __shared__ __align__(16) ushort_t Cs[128 * 128];
    __shared__ __align__(16) ushort_t Ws2[64 * 128];
    const int tid = threadIdx.x;
    const int wv = tid >> 6, lane = tid & 63;
    const int lo32 = lane & 31, g = lane >> 5;
    const int lrow = lane >> 4, lg = lane & 15;
    const int n0 = blockIdx.x * 64;
    const int m0 = blockIdx.y * 128;
    f32x16 a00 = Z16, a01 = Z16, a10 = Z16, a11 = Z16;
    for (int k0 = 0; k0 < D_; k0 += 128) {
        __syncthreads();
#pragma unroll
        for (int u = 0; u < 16; ++u) {
            int row = u * 8 + wv * 4 + lrow;
            int gs = lg ^ (row & 15);
            const ushort_t* src = ctxb + (size_t)(m0 + row) * D_ + k0 + gs * 8;
            gload16(src, (char*)Cs + (u * 8 + wv * 4) * 256);
        }
#pragma unroll
        for (int u = 0; u < 8; ++u) {
            int row = u * 8 + wv * 4 + lrow;
            int gs = lg ^ (row & 15);
            const ushort_t* src = wob + (size_t)(n0 + row) * D_ + k0 + gs * 8;
            gload16(src, (char*)Ws2 + (u * 8 + wv * 4) * 256);
        }
        __syncthreads();
#pragma unroll
        for (int ks = 0; ks < 8; ++ks) {
            int coff = ks * 16 + g * 8;
            int r0 = wv * 64 + lo32, r1 = r0 + 32;
            int n1 = lo32 + 32;
            short8 A0 = *(const short8*)&Cs[(r0 * 128 + coff) ^ ((r0 & 15) << 3)];
            short8 A1 = *(const short8*)&Cs[(r1 * 128 + coff) ^ ((r1 & 15) << 3)];
            short8 B0 = *(const short8*)&Ws2[(lo32 * 128 + coff) ^ ((lo32 & 15) << 3)];
            short8 B1 = *(const short8*)&Ws2[(n1 * 128 + coff) ^ ((n1 & 15) << 3)];
            a00 = MFMA(A0, B0, a00);
            a01 = MFMA(A0, B1, a01);
            a10 = MFMA(A1, B0, a10);
            a11 = MFMA(A1, B1, a11);
        }
    }
    float b0v = bo[n0 + lo32], b1v = bo[n0 + 32 + lo32];
#define OUT_STORE(ACC, MT, NT, BV)                                          \
    _Pragma("unroll")                                                       \
    for (int r = 0; r < 16; ++r) {                                          \
        int m = m0 + wv * 64 + (MT) * 32 + (r & 3) + 8 * (r >> 2) + 4 * g;  \
        int n = n0 + (NT) * 32 + lo32;                                      \
        Out[(size_t)m * D_ + n] = ACC[r] + (BV);                            \
    }
    OUT_STORE(a00, 0, 0, b0v)
    OUT_STORE(a01, 0, 1, b1v)
    OUT_STORE(a10, 1, 0, b0v)
    OUT_STORE(a11, 1, 1, b1v)
#undef OUT_STORE
}

// ---------------------------------------------------------------------------
extern "C" void kernel_launch(void* const* d_in, const int* in_sizes, int n_in,
                              void* d_out, int out_size, void* d_ws,
                              size_t ws_size, hipStream_t stream)
{
    const float* q = (const float*)d_in[0];
    const float* k = (const float*)d_in[1];
    const float* v = (const float*)d_in[2];
    const float* W_q = (const float*)d_in[3];
    const float* W_k = (const float*)d_in[4];
    const float* W_v = (const float*)d_in[5];
    const float* W_o = (const float*)d_in[6];
    const float* b_o = (const float*)d_in[7];
    float* out = (float*)d_out;

    ushort_t* wqt_h = (ushort_t*)d_ws;                 // 6 x 1M ushorts: weights
    ushort_t* wqt_l = wqt_h + (1 << 20);
    ushort_t* wkt_h = wqt_l + (1 << 20);
    ushort_t* wkt_l = wkt_h + (1 << 20);
    ushort_t* wvt_h = wkt_l + (1 << 20);
    ushort_t* wob   = wvt_h + (1 << 20);
    ushort_t* qh_h  = wob + (1 << 20);                 // 5 x 4M: proj outputs
    ushort_t* qh_l  = qh_h + (1 << 22);
    ushort_t* kh_h  = qh_l + (1 << 22);
    ushort_t* kh_l  = kh_h + (1 << 22);
    ushort_t* vhp   = kh_l + (1 << 22);
    ushort_t* Xh    = vhp + (1 << 22);                 // 12M: [3][2][S][D] hi
    ushort_t* Xl    = Xh + 3 * (1 << 22);              // 16M: [2][2][S][D] lo (q,k)
    ushort_t* ctxb  = Xh;                              // alias: Xh dead after proj
    ushort_t* Opart = Xl;                              // alias: Xl dead after proj
    float*    Ml    = (float*)(Xl + 2 * (size_t)(B_ * H_ * S_) * 64);

    cvtx_kernel<<<dim3(2048, 3), 256, 0, stream>>>(q, k, v, Xh, Xl);
    cvtw_kernel<<<dim3(16, 16, 3), 256, 0, stream>>>(
        W_q, W_k, W_v, wqt_h, wqt_l, wkt_h, wkt_l, wvt_h);
    cvtwo_kernel<<<1024, 256, 0, stream>>>(W_o, wob);
    proj_kernel<<<dim3(16, 8, 6), 256, 0, stream>>>(
        Xh, Xl, wqt_h, wqt_l, wkt_h, wkt_l, wvt_h,
        qh_h, qh_l, kh_h, kh_l, vhp);
    attn_kernel<<<dim3(16, 16, 4), 256, 0, stream>>>(
        qh_h, qh_l, kh_h, kh_l, vhp, Opart, Ml);
    merge_kernel<<<2048, 256, 0, stream>>>(Opart, Ml, ctxb);
    outproj_kernel<<<dim3(16, 32), 128, 0, stream>>>(ctxb, wob, b_o, out);
}